// Round 13
// baseline (390.279 us; speedup 1.0000x reference)
//
#include <hip/hip_runtime.h>

typedef unsigned short u16;
typedef __attribute__((ext_vector_type(8))) short s16x8;
typedef __attribute__((ext_vector_type(4))) float f32x4;
typedef __attribute__((ext_vector_type(8))) unsigned short u16x8;

__device__ inline float b2f(u16 u) {
  unsigned x = ((unsigned)u) << 16;
  return __builtin_bit_cast(float, x);
}
__device__ inline u16 f2b(float f) {
  unsigned u = __builtin_bit_cast(unsigned, f);
  u += 0x7fffu + ((u >> 16) & 1u);
  return (u16)(u >> 16);
}

#define GLL(src, dst) __builtin_amdgcn_global_load_lds( \
    (const __attribute__((address_space(1))) unsigned int*)(src), \
    (__attribute__((address_space(3))) unsigned int*)(dst), 16, 0, 0)

// ---------------------------------------------------------------------------
// Batched MFMA GEMM (proven): C = alpha*(A @ B^T) + beta*Aadd + bias.
// Score mode (Ws != null, BN==256): per-chunk epilogue writes PARTIAL row-dot
//   sc[bz*8192 + row] = sum_c acc[row][c]*Ws[c]   (combined in fused_tail).
// ---------------------------------------------------------------------------
struct MP {
  const u16* A; const u16* B;
  u16* C; u16* Ct; float* Cf; u16* vTo;
  const u16* Aadd; const float* bias;
  const float* Ws; float* sc;
  int M, N, K;
  int lda, ldb, ldc, ldct, ldcf, ldaadd;
  long long bA, bB, bC, bCt, bCf, bAadd;
  float alpha, beta;
  int relu, scale_cols; float colscale;
  int kchunks;
};

template<int BM, int BN, bool F32A>
__global__ __launch_bounds__(256) void gemm_mfma(MP p)
{
  constexpr int WM = BM / 2, WN = BN / 2;
  constexpr int FM = WM / 16, FN = WN / 16;
  constexpr int APAN = BM / 16, BPAN = BN / 16, NPAN = APAN + BPAN;
  constexpr int APW = (APAN + 3) / 4;
  __shared__ __align__(16) u16 lds[2 * NPAN * 512];

  const int tid = threadIdx.x, lane = tid & 63, wid = tid >> 6;
  const int bz = blockIdx.z;
  const int batch = (p.kchunks > 1) ? bz / p.kchunks : bz;
  const int kc    = (p.kchunks > 1) ? bz % p.kchunks : 0;
  const u16* A = p.A + (long long)batch * p.bA + (long long)kc * p.K;
  const float* Af32 = (const float*)p.A + (long long)batch * p.bA + (long long)kc * p.K;
  const u16* B = p.B + (long long)batch * p.bB + (long long)kc * p.K;
  const int m0 = blockIdx.y * BM, n0 = blockIdx.x * BN;
  const int srow = lane & 15, skoff = (lane >> 4) * 8;
  const int wm0 = (wid >> 1) * WM, wn0 = (wid & 1) * WN;

  f32x4 acc[FM][FN];
#pragma unroll
  for (int i = 0; i < FM; i++)
#pragma unroll
    for (int j = 0; j < FN; j++) acc[i][j] = (f32x4){0.f, 0.f, 0.f, 0.f};

  float4 areg[APW][2];

  auto stage_all = [&](int sb, int kt) {
#pragma unroll
    for (int pp = wid; pp < NPAN; pp += 4) {
      const u16* src = (pp < APAN)
        ? A + (size_t)(m0 + pp * 16 + srow) * p.lda + kt + skoff
        : B + (size_t)(n0 + (pp - APAN) * 16 + srow) * p.ldb + kt + skoff;
      GLL(src, &lds[sb * (NPAN * 512) + pp * 512]);
    }
  };
  auto stage_b = [&](int sb, int kt) {
#pragma unroll
    for (int pp = APAN + wid; pp < NPAN; pp += 4) {
      const u16* src = B + (size_t)(n0 + (pp - APAN) * 16 + srow) * p.ldb + kt + skoff;
      GLL(src, &lds[sb * (NPAN * 512) + pp * 512]);
    }
  };
  auto load_a = [&](int kt) {
#pragma unroll
    for (int ap = 0; ap < APW; ap++) {
      int pp = wid + ap * 4;
      const float* src = Af32 + (size_t)(m0 + pp * 16 + srow) * p.lda + kt + skoff;
      areg[ap][0] = ((const float4*)src)[0];
      areg[ap][1] = ((const float4*)src)[1];
    }
  };
  auto write_a = [&](int sb) {
#pragma unroll
    for (int ap = 0; ap < APW; ap++) {
      int pp = wid + ap * 4;
      u16 t[8];
      t[0] = f2b(areg[ap][0].x); t[1] = f2b(areg[ap][0].y);
      t[2] = f2b(areg[ap][0].z); t[3] = f2b(areg[ap][0].w);
      t[4] = f2b(areg[ap][1].x); t[5] = f2b(areg[ap][1].y);
      t[6] = f2b(areg[ap][1].z); t[7] = f2b(areg[ap][1].w);
      *(s16x8*)&lds[sb * (NPAN * 512) + pp * 512 + lane * 8] = *(const s16x8*)t;
    }
  };
  auto compute = [&](int sb) {
    const int bo = sb * (NPAN * 512);
    s16x8 afr[FM], bfr[FN];
#pragma unroll
    for (int i = 0; i < FM; i++)
      afr[i] = *(const s16x8*)&lds[bo + (wm0 / 16 + i) * 512 + lane * 8];
#pragma unroll
    for (int j = 0; j < FN; j++)
      bfr[j] = *(const s16x8*)&lds[bo + (APAN + wn0 / 16 + j) * 512 + lane * 8];
#pragma unroll
    for (int i = 0; i < FM; i++)
#pragma unroll
      for (int j = 0; j < FN; j++)
        acc[i][j] = __builtin_amdgcn_mfma_f32_16x16x32_bf16(afr[i], bfr[j], acc[i][j], 0, 0, 0);
  };

  const int nt = p.K / 32;
  int buf = 0;
  if constexpr (F32A) { load_a(0); stage_b(0, 0); write_a(0); }
  else                { stage_all(0, 0); }
  asm volatile("s_waitcnt vmcnt(0)" ::: "memory");
  __syncthreads();

  for (int t = 0; t < nt; ++t) {
    if constexpr (F32A) {
      if (t + 1 < nt) { load_a((t + 1) * 32); stage_b(buf ^ 1, (t + 1) * 32); }
      compute(buf);
      if (t + 1 < nt) write_a(buf ^ 1);
    } else {
      if (t + 1 < nt) stage_all(buf ^ 1, (t + 1) * 32);
      compute(buf);
    }
    asm volatile("s_waitcnt vmcnt(0)" ::: "memory");
    __syncthreads();
    buf ^= 1;
  }

  const int r0 = (lane >> 4) * 4, c0 = lane & 15;

  if (p.Ws) {
    // Partial score epilogue: per-row dot with Ws (no bias/relu — linear in K,
    // so split-K partials sum exactly; fused_tail combines + relu).
    float* sb = (float*)lds;   // [2 col-halves][64 rows]; safe after last sync
#pragma unroll
    for (int i = 0; i < FM; i++)
#pragma unroll
      for (int q = 0; q < 4; q++) {
        float s = 0.f;
#pragma unroll
        for (int j = 0; j < FN; j++)
          s += acc[i][j][q] * p.Ws[wn0 + j * 16 + c0];
        s += __shfl_xor(s, 1); s += __shfl_xor(s, 2);
        s += __shfl_xor(s, 4); s += __shfl_xor(s, 8);
        if ((lane & 15) == 0) sb[(wid & 1) * 64 + wm0 + i * 16 + r0 + q] = s;
      }
    __syncthreads();
    if (tid < 64)
      p.sc[(size_t)bz * 8192 + m0 + tid] = sb[tid] + sb[64 + tid];
    return;
  }

#pragma unroll
  for (int i = 0; i < FM; i++) {
#pragma unroll
    for (int j = 0; j < FN; j++) {
#pragma unroll
      for (int q = 0; q < 4; q++) {
        const int gr = m0 + wm0 + i * 16 + r0 + q;
        const int gc = n0 + wn0 + j * 16 + c0;
        float c = p.alpha * acc[i][j][q];
        if (p.Aadd) c += p.beta * b2f(p.Aadd[(long long)batch * p.bAadd + (size_t)gr * p.ldaadd + gc]);
        if (p.bias) c += p.bias[gc];
        if (gc < p.scale_cols) c *= p.colscale;
        if (p.relu) c = fmaxf(c, 0.f);
        if (p.Cf) p.Cf[(long long)bz * p.bCf + (size_t)gr * p.ldcf + gc] = c;
        u16 b = f2b(c);
        if (p.C)  p.C [(long long)batch * p.bC + (size_t)gr * p.ldc + gc] = b;
        if (p.Ct) p.Ct[(long long)batch * p.bCt + (size_t)gc * p.ldct + gr] = b;
        if (p.vTo && gc >= 1024) p.vTo[(size_t)(gc - 1024) * 8192 + gr] = b;
      }
    }
  }
}

// ---------------------------------------------------------------------------
// reduce_bias_bf16: sum 4 split-K f32 partials + bias + relu -> bf16.
// ---------------------------------------------------------------------------
__global__ void reduce_bias_bf16(const float* __restrict__ parts,
                                 const float* __restrict__ bias,
                                 u16* __restrict__ out)
{
  const int i4 = blockIdx.x * 256 + threadIdx.x;
  float4 s = ((const float4*)parts)[i4];
#pragma unroll
  for (int k = 1; k < 4; k++) {
    float4 v = ((const float4*)parts)[(size_t)k * 524288 + i4];
    s.x += v.x; s.y += v.y; s.z += v.z; s.w += v.w;
  }
  const float4 b = ((const float4*)bias)[i4 & 63];
  s.x = fmaxf(s.x + b.x, 0.f); s.y = fmaxf(s.y + b.y, 0.f);
  s.z = fmaxf(s.z + b.z, 0.f); s.w = fmaxf(s.w + b.w, 0.f);
  ushort4 o; o.x = f2b(s.x); o.y = f2b(s.y); o.z = f2b(s.z); o.w = f2b(s.w);
  ((ushort4*)out)[i4] = o;
}

// ---------------------------------------------------------------------------
// av_fused: softmax(q_l @ k^T) @ v without materializing S. Split-K 32
// (512 blocks = 2/CU for latency hiding; nt=8 serial phases per block).
// ---------------------------------------------------------------------------
struct AVF { const u16 *qkvb, *ql, *vT; float *Cf, *den; };

__global__ __launch_bounds__(256) void av_fused(AVF p)
{
  __shared__ __align__(16) u16 lds[20480];
  const int tid = threadIdx.x, lane = tid & 63, wid = tid >> 6;
  const int bz = blockIdx.z, head = bz >> 5, kc = bz & 31;
  const int m0 = blockIdx.y * 128;
  const int srow = lane & 15, skoff = (lane >> 4) * 8;
  const int r0 = (lane >> 4) * 4, c0 = lane & 15;
  const u16* Kb = p.qkvb + 512 + (size_t)(kc * 256) * 1536 + head * 64;
  const u16* Vb = p.vT + (size_t)head * 524288 + kc * 256;
  const u16* QL = p.ql + head * 16384 + (size_t)m0 * 64;

#pragma unroll
  for (int q = 0; q < 4; q++) {
    int pid = wid * 4 + q, pr = pid >> 1, kc2 = pid & 1;
    GLL(QL + (size_t)(pr * 16 + srow) * 64 + kc2 * 32 + skoff, &lds[pid * 512]);
  }
  auto stage_kv = [&](int sb, int t) {
    int kr = wid >> 1, kc2 = wid & 1;
    GLL(Kb + (size_t)(t * 32 + kr * 16 + srow) * 1536 + kc2 * 32 + skoff,
        &lds[8192 + sb * 2048 + wid * 512]);
    GLL(Vb + (size_t)(wid * 16 + srow) * 8192 + t * 32 + skoff,
        &lds[12288 + sb * 2048 + wid * 512]);
  };

  f32x4 acc[4][2];
#pragma unroll
  for (int i = 0; i < 4; i++)
#pragma unroll
    for (int j = 0; j < 2; j++) acc[i][j] = (f32x4){0.f, 0.f, 0.f, 0.f};
  float den[2][4];
#pragma unroll
  for (int i = 0; i < 2; i++)
#pragma unroll
    for (int q = 0; q < 4; q++) den[i][q] = 0.f;

  const int nt = 8;
  int buf = 0;
  stage_kv(0, 0);
  asm volatile("s_waitcnt vmcnt(0)" ::: "memory");
  __syncthreads();

  for (int t = 0; t < nt; ++t) {
    if (t + 1 < nt) stage_kv(buf ^ 1, t + 1);
    f32x4 s[2][2];
#pragma unroll
    for (int i = 0; i < 2; i++)
#pragma unroll
      for (int j = 0; j < 2; j++) s[i][j] = (f32x4){0.f, 0.f, 0.f, 0.f};
#pragma unroll
    for (int t2 = 0; t2 < 2; t2++) {
      s16x8 aq[2], bk[2];
#pragma unroll
      for (int i = 0; i < 2; i++)
        aq[i] = *(const s16x8*)&lds[((wid * 2 + i) * 2 + t2) * 512 + lane * 8];
#pragma unroll
      for (int j = 0; j < 2; j++)
        bk[j] = *(const s16x8*)&lds[8192 + buf * 2048 + (j * 2 + t2) * 512 + lane * 8];
#pragma unroll
      for (int i = 0; i < 2; i++)
#pragma unroll
        for (int j = 0; j < 2; j++)
          s[i][j] = __builtin_amdgcn_mfma_f32_16x16x32_bf16(aq[i], bk[j], s[i][j], 0, 0, 0);
    }
#pragma unroll
    for (int i = 0; i < 2; i++)
#pragma unroll
      for (int j = 0; j < 2; j++)
#pragma unroll
        for (int q = 0; q < 4; q++) {
          float e = expf(s[i][j][q]);
          den[i][q] += e;
          int kk = j * 16 + c0;
          lds[16384 + (wid * 2 + i) * 512 + (r0 + q) * 8 + (kk >> 3) * 128 + (kk & 7)] = f2b(e);
        }
    asm volatile("s_waitcnt vmcnt(0)" ::: "memory");
    __syncthreads();
    {
      s16x8 afr[4], bfr[2];
#pragma unroll
      for (int i = 0; i < 4; i++)
        afr[i] = *(const s16x8*)&lds[16384 + ((wid >> 1) * 4 + i) * 512 + lane * 8];
#pragma unroll
      for (int j = 0; j < 2; j++)
        bfr[j] = *(const s16x8*)&lds[12288 + buf * 2048 + ((wid & 1) * 2 + j) * 512 + lane * 8];
#pragma unroll
      for (int i = 0; i < 4; i++)
#pragma unroll
        for (int j = 0; j < 2; j++)
          acc[i][j] = __builtin_amdgcn_mfma_f32_16x16x32_bf16(afr[i], bfr[j], acc[i][j], 0, 0, 0);
    }
    __syncthreads();
    buf ^= 1;
  }

#pragma unroll
  for (int i = 0; i < 4; i++)
#pragma unroll
    for (int j = 0; j < 2; j++)
#pragma unroll
      for (int q = 0; q < 4; q++) {
        const int gr = m0 + (wid >> 1) * 64 + i * 16 + r0 + q;
        const int gc = (wid & 1) * 32 + j * 16 + c0;
        p.Cf[(size_t)bz * 16384 + (size_t)gr * 64 + gc] = acc[i][j][q];
      }
#pragma unroll
  for (int i = 0; i < 2; i++)
#pragma unroll
    for (int q = 0; q < 4; q++) {
      float v = den[i][q];
      v += __shfl_xor(v, 1); v += __shfl_xor(v, 2);
      v += __shfl_xor(v, 4); v += __shfl_xor(v, 8);
      if (c0 == 0)
        p.den[(size_t)bz * 256 + m0 + wid * 32 + i * 16 + r0 + q] = v;
    }
}

// ---------------------------------------------------------------------------
// fused_attn1 (r11-validated form, NO conv): af = softmax(q @ k_l^T) @ Mm.
// ---------------------------------------------------------------------------
struct FA1 { const u16 *qkvb, *kl, *MmT; u16 *af; };

__global__ __launch_bounds__(256) void fused_attn1(FA1 p)
{
  __shared__ __align__(16) u16 lds[36864];
  __shared__ float mb[4][64];
  const int tid = threadIdx.x, lane = tid & 63, wid = tid >> 6;
  const int head = blockIdx.y, n0 = blockIdx.x * 64;
  const int srow = lane & 15, skoff = (lane >> 4) * 8;
  const int rbase = (lane >> 4) * 4;

  for (int pid = wid; pid < 72; pid += 4) {
    const u16* src;
    if (pid < 8) {
      int pr = pid >> 1, kc = pid & 1;
      src = p.qkvb + (size_t)(n0 + pr * 16 + srow) * 1536 + head * 64 + kc * 32 + skoff;
    } else if (pid < 40) {
      int j = pid - 8, pr = j >> 1, kc = j & 1;
      src = p.kl + head * 16384 + (size_t)(pr * 16 + srow) * 64 + kc * 32 + skoff;
    } else {
      int j = pid - 40, pr = j >> 3, kc = j & 7;
      src = p.MmT + head * 16384 + (size_t)(pr * 16 + srow) * 256 + kc * 32 + skoff;
    }
    GLL(src, &lds[pid * 512]);
  }
  asm volatile("s_waitcnt vmcnt(0)" ::: "memory");
  __syncthreads();

  const int wr = (wid >> 1) * 32, ch_ = wid & 1;
  f32x4 s[2][8];
#pragma unroll
  for (int i = 0; i < 2; i++)
#pragma unroll
    for (int j = 0; j < 8; j++) s[i][j] = (f32x4){0.f, 0.f, 0.f, 0.f};
#pragma unroll
  for (int t = 0; t < 2; t++) {
    s16x8 a[2], b[8];
#pragma unroll
    for (int i = 0; i < 2; i++)
      a[i] = *(const s16x8*)&lds[(((wid >> 1) * 2 + i) * 2 + t) * 512 + lane * 8];
#pragma unroll
    for (int j = 0; j < 8; j++)
      b[j] = *(const s16x8*)&lds[4096 + ((ch_ * 8 + j) * 2 + t) * 512 + lane * 8];
#pragma unroll
    for (int i = 0; i < 2; i++)
#pragma unroll
      for (int j = 0; j < 8; j++)
        s[i][j] = __builtin_amdgcn_mfma_f32_16x16x32_bf16(a[i], b[j], s[i][j], 0, 0, 0);
  }
#pragma unroll
  for (int i = 0; i < 2; i++)
#pragma unroll
    for (int q = 0; q < 4; q++) {
      float rm = -INFINITY;
#pragma unroll
      for (int j = 0; j < 8; j++) rm = fmaxf(rm, s[i][j][q]);
#pragma unroll
      for (int off = 1; off < 16; off <<= 1) rm = fmaxf(rm, __shfl_xor(rm, off));
      if ((lane & 15) == 0) mb[ch_][wr + i * 16 + rbase + q] = rm;
    }
  __syncthreads();
  float m_[2][4];
#pragma unroll
  for (int i = 0; i < 2; i++)
#pragma unroll
    for (int q = 0; q < 4; q++)
      m_[i][q] = fmaxf(mb[0][wr + i * 16 + rbase + q], mb[1][wr + i * 16 + rbase + q]);
#pragma unroll
  for (int i = 0; i < 2; i++)
#pragma unroll
    for (int q = 0; q < 4; q++) {
      float ss = 0.f;
#pragma unroll
      for (int j = 0; j < 8; j++) {
        float e = expf(s[i][j][q] - m_[i][q]);
        s[i][j][q] = e; ss += e;
      }
#pragma unroll
      for (int off = 1; off < 16; off <<= 1) ss += __shfl_xor(ss, off);
      if ((lane & 15) == 0) mb[2 + ch_][wr + i * 16 + rbase + q] = ss;
    }
  __syncthreads();
#pragma unroll
  for (int i = 0; i < 2; i++)
#pragma unroll
    for (int q = 0; q < 4; q++) {
      int row = wr + i * 16 + rbase + q;
      float inv = 1.f / (mb[2][row] + mb[3][row]);
#pragma unroll
      for (int j = 0; j < 8; j++)
        lds[(size_t)row * 264 + ch_ * 128 + j * 16 + (lane & 15)] = f2b(s[i][j][q] * inv);
    }
  __syncthreads();
  const int wr2 = (wid >> 1) * 32, wd2 = (wid & 1) * 32;
  f32x4 acc[2][2];
#pragma unroll
  for (int i = 0; i < 2; i++)
#pragma unroll
    for (int jd = 0; jd < 2; jd++) acc[i][jd] = (f32x4){0.f, 0.f, 0.f, 0.f};
#pragma unroll
  for (int t = 0; t < 8; t++) {
    s16x8 a[2], b[2];
#pragma unroll
    for (int i = 0; i < 2; i++)
      a[i] = *(const s16x8*)&lds[(size_t)(wr2 + i * 16 + (lane & 15)) * 264 + t * 32 + (lane >> 4) * 8];
#pragma unroll
    for (int jd = 0; jd < 2; jd++)
      b[jd] = *(const s16x8*)&lds[20480 + (((wid & 1) * 2 + jd) * 8 + t) * 512 + lane * 8];
#pragma unroll
    for (int i = 0; i < 2; i++)
#pragma unroll
      for (int jd = 0; jd < 2; jd++)
        acc[i][jd] = __builtin_amdgcn_mfma_f32_16x16x32_bf16(a[i], b[jd], acc[i][jd], 0, 0, 0);
  }
#pragma unroll
  for (int i = 0; i < 2; i++)
#pragma unroll
    for (int jd = 0; jd < 2; jd++)
#pragma unroll
      for (int q = 0; q < 4; q++)
        p.af[(size_t)(n0 + wr2 + i * 16 + rbase + q) * 512 + head * 64 + wd2 + jd * 16 + (lane & 15)]
            = f2b(acc[i][jd][q]);
}

// ---------------------------------------------------------------------------
// conv_res_add_bf16 (proven standalone; wave = 64 consecutive ch in one row)
// ---------------------------------------------------------------------------
__global__ void conv_res_add_bf16(const u16* __restrict__ qkvb,
                                  const float* __restrict__ convw,
                                  u16* __restrict__ af)
{
  __shared__ float vt[96][64];
  const int h = blockIdx.y, n0 = blockIdx.x * 64;
  const int t = threadIdx.x, ch = t & 63, r0 = t >> 6;
  for (int r = r0; r < 96; r += 4) {
    int n = n0 - 16 + r;
    float v = 0.f;
    if (n >= 0 && n < 8192) v = b2f(qkvb[(size_t)n * 1536 + 1024 + h * 64 + ch]);
    vt[r][ch] = v;
  }
  __syncthreads();
  float w[33];
#pragma unroll
  for (int j = 0; j < 33; j++) w[j] = convw[h * 33 + j];
  for (int tl = r0; tl < 64; tl += 4) {
    float acc = 0.f;
#pragma unroll
    for (int j = 0; j < 33; j++) acc += w[j] * vt[tl + j][ch];
    size_t o = (size_t)(n0 + tl) * 512 + h * 64 + ch;
    af[o] = f2b(b2f(af[o]) + acc);
  }
}

// ---------------------------------------------------------------------------
// fused_tail v2: blocks 0..7 = aggregated column-groups (coalesced hb reads:
// lane = column, 2x64B exact cachelines per wave; softmax weights staged in
// LDS). Block 8 = weights output (bit-identical to prior version).
// ---------------------------------------------------------------------------
__global__ void fused_tail(const float* __restrict__ sp,
                           const float* __restrict__ wconst,
                           const u16* __restrict__ hb, float* __restrict__ out)
{
  __shared__ float red[256];
  __shared__ float wlds[8192];
  const int t = threadIdx.x, bg = blockIdx.x;
  const float wc = wconst[0];
  float e[32];
  float m = -INFINITY;
#pragma unroll
  for (int i = 0; i < 32; i++) {
    int idx = t + i * 256;
    float v = sp[idx] + sp[8192 + idx] + sp[16384 + idx] + sp[24576 + idx] + wc;
    v = fmaxf(v, 0.f);
    e[i] = v; m = fmaxf(m, v);
  }
  red[t] = m; __syncthreads();
  for (int s = 128; s; s >>= 1) { if (t < s) red[t] = fmaxf(red[t], red[t + s]); __syncthreads(); }
  m = red[0]; __syncthreads();
  float ls = 0.f;
#pragma unroll
  for (int i = 0; i < 32; i++) { e[i] = expf(e[i] - m); ls += e[i]; }
  red[t] = ls; __syncthreads();
  for (int s = 128; s; s >>= 1) { if (t < s) red[t] += red[t + s]; __syncthreads(); }
  const float inv = 1.f / red[0];
  __syncthreads();

  if (bg == 8) {
#pragma unroll
    for (int i = 0; i < 32; i++) out[256 + t + i * 256] = e[i] * inv;
    return;
  }

  // aggregated: block bg owns columns [bg*32, bg*32+32)
#pragma unroll
  for (int i = 0; i < 32; i++) wlds[t + i * 256] = e[i] * inv;
  __syncthreads();
  const int colo = t & 31, nslot = t >> 5;
  const int c = bg * 32 + colo;
  float acc = 0.f;
#pragma unroll 4
  for (int n = nslot; n < 8192; n += 8)
    acc += wlds[n] * b2f(hb[(size_t)n * 256 + c]);
  red[t] = acc; __syncthreads();
  if (t < 32) {
    float s = 0.f;
#pragma unroll
    for (int sx = 0; sx < 8; sx++) s += red[sx * 32 + t];
    out[bg * 32 + t] = s;
  }
}

// ---------------------------------------------------------------------------
// prescale: 16 blocks — blocks 0..7 row-abs-sum max (rs), 8..15 col (cs).
// ---------------------------------------------------------------------------
__global__ void prescale(const u16* __restrict__ x2, float* __restrict__ sbuf)
{
  const int h = blockIdx.x & 7, which = blockIdx.x >> 3, t = threadIdx.x;
  const u16* X = x2 + ((size_t)h << 16);
  __shared__ float red[256];
  float s = 0.f;
  if (which == 0) {
    for (int c4 = 0; c4 < 256; c4 += 4) {
      ushort4 v = *(const ushort4*)(X + (size_t)t * 256 + c4);
      s += fabsf(b2f(v.x)) + fabsf(b2f(v.y)) + fabsf(b2f(v.z)) + fabsf(b2f(v.w));
    }
  } else {
    for (int r = 0; r < 256; r++) s += fabsf(b2f(X[r * 256 + t]));
  }
  red[t] = s; __syncthreads();
  for (int st = 128; st; st >>= 1) {
    if (t < st) red[t] = fmaxf(red[t], red[t + st]);
    __syncthreads();
  }
  if (t == 0) sbuf[which * 8 + h] = red[0];
}

__global__ void pinv_init(const u16* __restrict__ x2, const float* __restrict__ sbuf,
                          u16* __restrict__ z0, u16* __restrict__ z0T)
{
  __shared__ u16 tile[64][80];
  const int t = threadIdx.x;
  const size_t base = (size_t)blockIdx.y << 16;
  const int tr = (blockIdx.x >> 2) * 64, tc = (blockIdx.x & 3) * 64;
  const u16* X = x2 + base;

  float mr = -INFINITY, mc = -INFINITY;
#pragma unroll
  for (int i = 0; i < 8; i++) {
    mr = fmaxf(mr, sbuf[i]);
    mc = fmaxf(mc, sbuf[8 + i]);
  }
  const float inv = 1.f / (mr * mc);

  {
    int r = t >> 2, cg = (t & 3) * 16;
#pragma unroll
    for (int v4 = 0; v4 < 4; v4++) {
      ushort4 v = *(const ushort4*)(X + (size_t)(tr + r) * 256 + tc + cg + v4 * 4);
      v.x = f2b(b2f(v.x) * inv); v.y = f2b(b2f(v.y) * inv);
      v.z = f2b(b2f(v.z) * inv); v.w = f2b(b2f(v.w) * inv);
      *(ushort4*)(z0T + base + (size_t)(tr + r) * 256 + tc + cg + v4 * 4) = v;
      *(ushort4*)&tile[r][cg + v4 * 4] = v;
    }
  }
  __syncthreads();
  {
    int c = t >> 2, rg = (t & 3) * 16;
    u16 o[16];
#pragma unroll
    for (int e = 0; e < 16; e++) o[e] = tile[rg + e][c];
#pragma unroll
    for (int v4 = 0; v4 < 4; v4++)
      *(ushort4*)(z0 + base + (size_t)(tc + c) * 256 + tr + rg + v4 * 4) = *(ushort4*)&o[v4 * 4];
  }
}

// ---------------------------------------------------------------------------
// pinv_gemm: kept for the one-time A0 = x2 @ z0 (writes A0 and A0^T).
// ---------------------------------------------------------------------------
struct PG {
  const u16 *U, *V, *Xadd, *XaddT;
  u16 *DR, *DT;
  float alpha, beta;
};

template<bool WD, bool WDT>
__global__ __launch_bounds__(256) void pinv_gemm(PG p)
{
  __shared__ __align__(16) u16 lds[65536 / 2];
  const int tid = threadIdx.x, lane = tid & 63, wid = tid >> 6;
  const size_t base = (size_t)blockIdx.z << 16;
  const u16* U = p.U + base;
  const u16* V = p.V + base;
  const int m0 = blockIdx.y * 64, n0 = blockIdx.x * 64;
  const int srow = lane & 15, skoff = (lane >> 4) * 8;
  const int wr = (wid >> 1) * 32, wc = (wid & 1) * 32;

#pragma unroll
  for (int q = 0; q < 16; q++) {
    const int pid = wid * 16 + q;
    const int rg = (pid >> 3) & 3, t = pid & 7;
    const u16* src = (pid < 32)
      ? U + (size_t)(m0 + rg * 16 + srow) * 256 + t * 32 + skoff
      : V + (size_t)(n0 + rg * 16 + srow) * 256 + t * 32 + skoff;
    GLL(src, &lds[pid * 512]);
  }
  asm volatile("s_waitcnt vmcnt(0)" ::: "memory");
  __syncthreads();

  f32x4 acc[2][2], accT[2][2];
#pragma unroll
  for (int i = 0; i < 2; i++)
#pragma unroll
    for (int j = 0; j < 2; j++) {
      acc[i][j] = (f32x4){0.f, 0.f, 0.f, 0.f};
      accT[i][j] = (f32x4){0.f, 0.f, 0.f, 0.f};
    }

#pragma unroll
  for (int t = 0; t < 8; t++) {
    s16x8 afr[2], bfr[2];
#pragma unroll
    for (int i = 0; i < 2; i++)
      afr[i] = *(const s16x8*)&lds[((wr / 16 + i) * 8 + t) * 512 + lane * 8];
#pragma unroll
    for (int j = 0; j < 2; j++)
      bfr[j] = *(const s16x8*)&lds[(32 + (wc / 16 + j) * 8 + t) * 512 + lane * 8];
#pragma unroll
    for (int i = 0; i < 2; i++)
#pragma unroll
      for (int j = 0; j < 2; j++) {
        if constexpr (WD)
          acc[i][j] = __builtin_amdgcn_mfma_f32_16x16x32_bf16(afr[i], bfr[j], acc[i][j], 0, 0, 0);
        if constexpr (WDT)
          accT[j][i] = __builtin_amdgcn_mfma_f32_16x16x32_bf16(bfr[j], afr[i], accT[j][i], 0, 0, 0);
      }
  }

  const int r0 = (lane >> 4) * 4, c0 = lane & 15;
  if constexpr (WD) {
    const u16* Xa = p.Xadd ? p.Xadd + base : nullptr;
    u16* DR = p.DR + base;
#pragma unroll
    for (int i = 0; i < 2; i++)
#pragma unroll
      for (int j = 0; j < 2; j++)
#pragma unroll
        for (int q = 0; q < 4; q++) {
          const int gr = m0 + wr + i * 16 + r0 + q;
          const int gc = n0 + wc + j * 16 + c0;
          float v = p.alpha * acc[i][j][q];
          if (Xa) v += p.beta * b2f(Xa[(size_t)gr * 256 + gc]);
          DR[(size_t)gr * 256 + gc] = f2b(v);
        }
  }
  if constexpr (WDT) {
    const u16* Xt = p.XaddT ? p.XaddT + base : nullptr;
    u16* DT = p.DT + base;
#pragma unroll
    for (int j = 0; j < 2; j++)
#pragma unroll
      for (int i = 0; i < 2; i++)
#pragma unroll
        for (int q = 0; q < 4; q++) {
          const int gn = n0 + wc + j * 16 + r0 + q;
          const int gm = m0 + wr + i * 16 + c0;
          float v = p.alpha * accT[j][i][q];
          if (Xt) v += p.beta * b2f(Xt[(size_t)gn * 256 + gm]);
          DT[(size_t)gn * 256 + gm] = f2b(v);
        }
  }
}

// ---------------------------------------------------------------------------
// Depth-2 pinv iteration (coupled A,z form; A = x@z invariant):
//   B = A@A, G = 7A - B, W = z@A
//   z' = 0.25*(W@G) + 3.25*z - 3.75*W
//   A' = 0.25*(G@B) + 3.25*A - 3.75*B      ( = x@z' in exact arithmetic )
// ---------------------------------------------------------------------------
struct PR1 { const u16 *A, *At, *z; u16 *B, *Bt, *G, *Gt, *W; };

__global__ __launch_bounds__(256) void pinv_r1(PR1 p)
{
  __shared__ __align__(16) u16 lds[32768];
  const int tid = threadIdx.x, lane = tid & 63, wid = tid >> 6;
  const int prob = blockIdx.z >> 3;
  const size_t base = (size_t)(blockIdx.z & 7) << 16;
  const u16* U = (prob ? p.z : p.A) + base;
  const u16* V = p.At + base;
  const int m0 = blockIdx.y * 64, n0 = blockIdx.x * 64;
  const int srow = lane & 15, skoff = (lane >> 4) * 8;
  const int wr = (wid >> 1) * 32, wc = (wid & 1) * 32;

#pragma unroll
  for (int q = 0; q < 16; q++) {
    const int pid = wid * 16 + q;
    const int rg = (pid >> 3) & 3, t = pid & 7;
    const u16* src = (pid < 32)
      ? U + (size_t)(m0 + rg * 16 + srow) * 256 + t * 32 + skoff
      : V + (size_t)(n0 + rg * 16 + srow) * 256 + t * 32 + skoff;
    GLL(src, &lds[pid * 512]);
  }
  asm volatile("s_waitcnt vmcnt(0)" ::: "memory");
  __syncthreads();

  f32x4 acc[2][2], accT[2][2];
#pragma unroll
  for (int i = 0; i < 2; i++)
#pragma unroll
    for (int j = 0; j < 2; j++) {
      acc[i][j] = (f32x4){0.f, 0.f, 0.f, 0.f};
      accT[i][j] = (f32x4){0.f, 0.f, 0.f, 0.f};
    }

#pragma unroll
  for (int t = 0; t < 8; t++) {
    s16x8 afr[2], bfr[2];
#pragma unroll
    for (int i = 0; i < 2; i++)
      afr[i] = *(const s16x8*)&lds[((wr / 16 + i) * 8 + t) * 512 + lane * 8];
#pragma unroll
    for (int j = 0; j < 2; j++)
      bfr[j] = *(const s16x8*)&lds[(32 + (wc / 16 + j) * 8 + t) * 512 + lane * 8];
#pragma unroll
    for (int i = 0; i < 2; i++)
#pragma unroll
      for (int j = 0; j < 2; j++) {
        acc[i][j] = __builtin_amdgcn_mfma_f32_16x16x32_bf16(afr[i], bfr[j], acc[i][j], 0, 0, 0);
        if (prob == 0)
          accT[j][i] = __builtin_amdgcn_mfma_f32_16x16x32_bf16(bfr[j], afr[i], accT[j][i], 0, 0, 0);
      }
  }

  const int r0 = (lane >> 4) * 4, c0 = lane & 15;
  if (prob == 0) {
    const u16* Ab  = p.A  + base;
    const u16* Atb = p.At + base;
    u16 *Bv = p.B + base, *Btv = p.Bt + base;
    u16 *Gv = p.G + base, *Gtv = p.Gt + base;
#pragma unroll
    for (int i = 0; i < 2; i++)
#pragma unroll
      for (int j = 0; j < 2; j++)
#pragma unroll
        for (int q = 0; q < 4; q++) {
          const int gr = m0 + wr + i * 16 + r0 + q;
          const int gc = n0 + wc + j * 16 + c0;
          float b = acc[i][j][q];
          float a = b2f(Ab[(size_t)gr * 256 + gc]);
          Bv[(size_t)gr * 256 + gc] = f2b(b);
          Gv[(size_t)gr * 256 + gc] = f2b(7.f * a - b);
        }
#pragma unroll
    for (int j = 0; j < 2; j++)
#pragma unroll
      for (int i = 0; i < 2; i++)
#pragma unroll
        for (int q = 0; q < 4; q++) {
          const int gn = n0 + wc + j * 16 + r0 + q;
          const int gm = m0 + wr + i * 16 + c0;
          float bt = accT[j][i][q];
          float at = b2f(Atb[(size_t)gn * 256 + gm]);
          Btv[(size_t)gn * 256 + gm] = f2b(bt);
          Gtv[(size_t)gn * 256 + gm] = f2b(7.f * at - bt);
        }
  } else {
    u16* Wv = p.W + base;
#pragma unroll
    for (int i = 0; i < 2; i++)
#pragma unroll
      for (int j = 0; j < 2; j++)
#pragma unroll
        for (int q = 0; q < 4; q++) {
          const int gr = m0 + wr + i * 16 + r0 + q;
          const int gc = n0 + wc + j * 16 + c0;
          Wv[(size_t)gr * 256 + gc] = f2b(acc[i][j][q]);
        }
  }
}

struct PR2 { const u16 *W, *G, *Gt, *B, *Bt, *z, *A, *At; u16 *zo, *Ao, *Aot; };

__global__ __launch_bounds__(256) void pinv_r2(PR2 p)
{
  __shared__ __align__(16) u16 lds[32768];
  const int tid = threadIdx.x, lane = tid & 63, wid = tid >> 6;
  const int prob = blockIdx.z >> 3;
  const size_t base = (size_t)(blockIdx.z & 7) << 16;
  const u16* U = (prob ? p.G  : p.W ) + base;
  const u16* V = (prob ? p.Bt : p.Gt) + base;
  const int m0 = blockIdx.y * 64, n0 = blockIdx.x * 64;
  const int srow = lane & 15, skoff = (lane >> 4) * 8;
  const int wr = (wid >> 1) * 32, wc = (wid & 1) * 32;

#pragma unroll
  for (int q = 0; q < 16; q++) {
    const int pid = wid * 16 + q;
    const int rg = (pid >> 3) & 3, t = pid & 7;
    const u16* src = (pid < 32)
      ? U + (size_t)(m0 + rg * 16 + srow) * 256 + t * 32 + skoff
      : V + (size_t)(n0 + rg * 16 + srow) * 256 + t * 32 + skoff;
    GLL(src, &lds[pid * 512]);
  }
  asm volatile("s_waitcnt vmcnt(0)" ::: "memory");
  __syncthreads();

  f32x4 acc[2][2], accT[2][2];
#pragma unroll
  for (int i = 0; i < 2; i++)
#pragma unroll
    for (int j = 0; j < 2; j++) {
      acc[i][j] = (f32x4){0.f, 0.f, 0.f, 0.f};
      accT[i][j] = (f32x4){0.f, 0.f, 0.f, 0.f};
    }

#pragma unroll
  for (int t = 0; t < 8; t++) {
    s16x8 afr[2], bfr[2];
#pragma unroll
    for (int i = 0; i < 2; i++)
      afr[i] = *(const s16x8*)&lds[((wr / 16 + i) * 8 + t) * 512 + lane * 8];
#pragma unroll
    for (int j = 0; j < 2; j++)
      bfr[j] = *(const s16x8*)&lds[(32 + (wc / 16 + j) * 8 + t) * 512 + lane * 8];
#pragma unroll
    for (int i = 0; i < 2; i++)
#pragma unroll
      for (int j = 0; j < 2; j++) {
        acc[i][j] = __builtin_amdgcn_mfma_f32_16x16x32_bf16(afr[i], bfr[j], acc[i][j], 0, 0, 0);
        if (prob)
          accT[j][i] = __builtin_amdgcn_mfma_f32_16x16x32_bf16(bfr[j], afr[i], accT[j][i], 0, 0, 0);
      }
  }

  const int r0 = (lane >> 4) * 4, c0 = lane & 15;
  if (prob == 0) {
    const u16* Zb = p.z + base;
    const u16* Wb = p.W + base;
    u16* Zo = p.zo + base;
#pragma unroll
    for (int i = 0; i < 2; i++)
#pragma unroll
      for (int j = 0; j < 2; j++)
#pragma unroll
        for (int q = 0; q < 4; q++) {
          const int gr = m0 + wr + i * 16 + r0 + q;
          const int gc = n0 + wc + j * 16 + c0;
          float v = 0.25f * acc[i][j][q]
                  + 3.25f * b2f(Zb[(size_t)gr * 256 + gc])
                  - 3.75f * b2f(Wb[(size_t)gr * 256 + gc]);
          Zo[(size_t)gr * 256 + gc] = f2b(v);
        }
  } else {
    const u16* Ab  = p.A  + base;
    const u16* Bb  = p.B  + base;
    const u16* Atb = p.At + base;
    const u16* Btb = p.Bt + base;
    u16* Ao  = p.Ao  + base;
    u16* Aot = p.Aot + base;
#pragma unroll
    for (int i = 0; i < 2; i++)
#pragma unroll
      for (int j = 0; j < 2; j++)
#pragma unroll
        for (int q = 0; q < 4; q++) {
          const int gr = m0 + wr + i * 16 + r0 + q;
          const int gc = n0 + wc + j * 16 + c0;
          float v = 0.25f * acc[i][j][q]
                  + 3.25f * b2f(Ab[(size_t)gr * 256 + gc])
                  - 3.75f * b2f(Bb[(size_t)gr * 256 + gc]);
          Ao[(size_t)gr * 256 + gc] = f2b(v);
        }
#pragma unroll
    for (int j = 0; j < 2; j++)
#pragma unroll
      for (int i = 0; i < 2; i++)
#pragma unroll
        for (int q = 0; q < 4; q++) {
          const int gn = n0 + wc + j * 16 + r0 + q;
          const int gm = m0 + wr + i * 16 + c0;
          float v = 0.25f * accT[j][i][q]
                  + 3.25f * b2f(Atb[(size_t)gn * 256 + gm])
                  - 3.75f * b2f(Btb[(size_t)gn * 256 + gm]);
          Aot[(size_t)gn * 256 + gm] = f2b(v);
        }
  }
}

// ---------------------------------------------------------------------------
// prep_weights v2: 64x64 LDS tile transposes — coalesced 256B reads of the
// COLD weight matrices (old version read at per-lane stride 1-6KB = 1/16 line
// utilization ~ 48MB of HBM for 3MB of data). tile[64][65]: stride-65 access
// = 2 lanes/bank (free). Per-element f2b identical -> bitwise same outputs.
// Grid: 192 blocks (64 Wft + 96 Wqkv + 32 Wout).
// ---------------------------------------------------------------------------
__global__ void prep_weights(const float* __restrict__ Wft, const float* __restrict__ Wqkv,
                             const float* __restrict__ Wout, u16* __restrict__ WftT,
                             u16* __restrict__ WqkvT, u16* __restrict__ WoutT,
                             const float* __restrict__ bout, const float* __restrict__ Wsc,
                             const float* __restrict__ bsc, float* __restrict__ wconst)
{
  __shared__ float tile[64][65];
  const int t = threadIdx.x, col = t & 63, rowg = t >> 6;
  const int b = blockIdx.x;
  const float* src; u16* dst; int ldS, ldD, tr, tc;
  if (b < 64)       { src = Wft;  dst = WftT;  ldS = 256;  ldD = 1024;
                      tr = (b >> 2) * 64;  tc = (b & 3) * 64; }
  else if (b < 160) { int bb = b - 64;  src = Wqkv; dst = WqkvT; ldS = 1536; ldD = 256;
                      tr = (bb / 24) * 64; tc = (bb % 24) * 64; }
  else              { int bb = b - 160; src = Wout; dst = WoutT; ldS = 256;  ldD = 512;
                      tr = (bb >> 2) * 64; tc = (bb & 3) * 64; }
  for (int r = rowg; r < 64; r += 4)
    tile[r][col] = src[(size_t)(tr + r) * ldS + tc + col];
  __syncthreads();
  for (int r = rowg; r < 64; r += 4)
    dst[(size_t)(tc + r) * ldD + tr + col] = f2b(tile[col][r]);

  if (b == 0 && t < 64) {
    // wconst = sum_c b_out[c]*W_score[c] + b_score  (score-combine constant)
    int c = t * 4;
    float s = bout[c] * Wsc[c] + bout[c + 1] * Wsc[c + 1]
            + bout[c + 2] * Wsc[c + 2] + bout[c + 3] * Wsc[c + 3];
    for (int off = 1; off < 64; off <<= 1) s += __shfl_xor(s, off);
    if (t == 0) wconst[0] = s + bsc[0];
  }
}

__global__ void landmark_means(const u16* __restrict__ qkvb,
                               u16* __restrict__ ql, u16* __restrict__ kl)
{
  int idx = blockIdx.x * 256 + threadIdx.x;
  int which = idx >> 17, r = idx & 131071;
  int h = r >> 14, m = (r >> 6) & 255, d = r & 63;
  const u16* src = qkvb + (which ? 512 : 0) + h * 64 + d;
  float s = 0.f; int n0 = m * 32;
  for (int i = 0; i < 32; i++) s += b2f(src[(size_t)(n0 + i) * 1536]);
  (which ? kl : ql)[r] = f2b(s * (1.f / 32.f));
}

__global__ void softmax_rows_bf16_256(u16* __restrict__ d)
{
  const int row = blockIdx.x * 4 + (threadIdx.x >> 6);
  const int lane = threadIdx.x & 63;
  ushort4* p = (ushort4*)(d + (size_t)row * 256);
  ushort4 raw = p[lane];
  float v0 = b2f(raw.x), v1 = b2f(raw.y), v2 = b2f(raw.z), v3 = b2f(raw.w);
  float mx = fmaxf(fmaxf(v0, v1), fmaxf(v2, v3));
  for (int off = 1; off < 64; off <<= 1) mx = fmaxf(mx, __shfl_xor(mx, off));
  v0 = expf(v0 - mx); v1 = expf(v1 - mx); v2 = expf(v2 - mx); v3 = expf(v3 - mx);
  float s = v0 + v1 + v2 + v3;
  for (int off = 1; off < 64; off <<= 1) s += __shfl_xor(s, off);
  float inv = 1.f / s;
  raw.x = f2b(v0 * inv); raw.y = f2b(v1 * inv); raw.z = f2b(v2 * inv); raw.w = f2b(v3 * inv);
  p[lane] = raw;
}

// ---------------------------------------------------------------------------
// reduce_avT (R12-validated): lane index = d -> coalesced avp reads.
// ---------------------------------------------------------------------------
__global__ void reduce_avT(const float* __restrict__ avp, const float* __restrict__ den,
                           u16* __restrict__ avT)
{
  int idx = blockIdx.x * 256 + threadIdx.x;
  int d = idx & 63, m = (idx >> 6) & 255, h = idx >> 14;
  float s = 0.f, l = 0.f;
  for (int c = 0; c < 32; c++) {
    s += avp[((size_t)(h * 32 + c)) * 16384 + m * 64 + d];
    l += den[(size_t)(h * 32 + c) * 256 + m];
  }
  avT[((size_t)h * 64 + d) * 256 + m] = f2b(s / l);
}

// ---------------------------------------------------------------------------
extern "C" void kernel_launch(void* const* d_in, const int* in_sizes, int n_in,
                              void* d_out, int out_size, void* d_ws, size_t ws_size,
                              hipStream_t stream)
{
  const float* x       = (const float*)d_in[0];
  const float* W_ft    = (const float*)d_in[1];
  const float* b_ft    = (const float*)d_in[2];
  const float* W_qkv   = (const float*)d_in[3];
  const float* W_out   = (const float*)d_in[4];
  const float* b_out   = (const float*)d_in[5];
  const float* conv_w  = (const float*)d_in[6];
  const float* W_score = (const float*)d_in[7];
  const float* b_score = (const float*)d_in[8];
  float* out = (float*)d_out;

  char* W = (char*)d_ws;
  auto alloc = [&](size_t bytes) { char* r = W; W += (bytes + 255) & ~(size_t)255; return r; };
  u16* WftT  = (u16*)alloc(256ull * 1024 * 2);
  u16* WqkvT = (u16*)alloc(1536ull * 256 * 2);
  u16* WoutT = (u16*)alloc(256ull * 512 * 2);
  u16* hb    = (u16*)alloc(8192ull * 256 * 2);
  u16* qkvb  = (u16*)alloc(8192ull * 1536 * 2);
  u16* ql    = (u16*)alloc(8ull * 256 * 64 * 2);
  u16* kl    = (u16*)alloc(8ull * 256 * 64 * 2);
  u16* x2    = (u16*)alloc(8ull * 256 * 256 * 2);
  u16* z0    = (u16*)alloc(8ull * 256 * 256 * 2);
  u16* z0T   = (u16*)alloc(8ull * 256 * 256 * 2);
  u16* zp    = (u16*)alloc(8ull * 256 * 256 * 2);   // z pong
  u16* Amat  = (u16*)alloc(8ull * 256 * 256 * 2);   // A ping
  u16* AmatT = (u16*)alloc(8ull * 256 * 256 * 2);
  u16* Am2   = (u16*)alloc(8ull * 256 * 256 * 2);   // A pong
  u16* Am2T  = (u16*)alloc(8ull * 256 * 256 * 2);
  u16* Bm    = (u16*)alloc(8ull * 256 * 256 * 2);   // B = A@A
  u16* BmT   = (u16*)alloc(8ull * 256 * 256 * 2);
  u16* Gm    = (u16*)alloc(8ull * 256 * 256 * 2);   // G = 7A - B
  u16* GmT   = (u16*)alloc(8ull * 256 * 256 * 2);
  u16* Wm    = (u16*)alloc(8ull * 256 * 256 * 2);   // W = z@A
  u16* vT    = (u16*)alloc(8ull * 64 * 8192 * 2);
  float* avp = (float*)alloc(256ull * 16384 * 4);   // split-K 32 partials
  float* denp = (float*)alloc(256ull * 256 * 4);    // exp(S) chunk row-sums
  u16* avT   = (u16*)alloc(8ull * 64 * 256 * 2);
  u16* MmT   = (u16*)alloc(8ull * 64 * 256 * 2);
  u16* af    = (u16*)alloc(8192ull * 512 * 2);
  float* gpart = (float*)alloc(4ull * 8192 * 256 * 4);
  float* sbuf   = (float*)alloc(256);
  float* scores = (float*)alloc(4ull * 8192 * 4);   // split-K score partials
  float* wconst = (float*)alloc(256);

  auto mp = [](const u16* A, const u16* B, int M, int N, int K,
               int lda, int ldb, long long bA, long long bB) {
    MP p{}; p.A = A; p.B = B; p.M = M; p.N = N; p.K = K;
    p.lda = lda; p.ldb = ldb; p.bA = bA; p.bB = bB;
    p.alpha = 1.f; p.beta = 0.f; p.kchunks = 1; return p;
  };

  // 0) weight prep — tiled transposes (coalesced cold-HBM reads) + wconst
  prep_weights<<<192, 256, 0, stream>>>(W_ft, W_qkv, W_out, WftT, WqkvT, WoutT,
                                        b_out, W_score, b_score, wconst);

  // 1) h = relu(x @ W_ft + b_ft) — split-K x4 (proven) + fused reduce
  { MP p = mp((const u16*)x, WftT, 8192, 256, 256, 1024, 1024, 0, 0);
    p.kchunks = 4; p.Cf = gpart; p.ldcf = 256; p.bCf = 2097152;
    gemm_mfma<64, 256, true><<<dim3(1, 128, 4), 256, 0, stream>>>(p); }
  reduce_bias_bf16<<<2048, 256, 0, stream>>>(gpart, b_ft, hb);

  // 2) qkv = h @ W_qkv (q cols x0.125; v side-written transposed)
  { MP p = mp(hb, WqkvT, 8192, 1536, 256, 256, 256, 0, 0);
    p.C = qkvb; p.ldc = 1536; p.scale_cols = 512; p.colscale = 0.125f; p.vTo = vT;
    gemm_mfma<128, 128, false><<<dim3(12, 64, 1), 256, 0, stream>>>(p); }

  // 3) landmark means
  landmark_means<<<1024, 256, 0, stream>>>(qkvb, ql, kl);

  // 4) sim2 = q_l @ k_l^T ; softmax -> attn2 (x2)
  { MP p = mp(ql, kl, 256, 256, 64, 64, 64, 16384, 16384);
    p.C = x2; p.ldc = 256; p.bC = 65536;
    gemm_mfma<64, 64, false><<<dim3(4, 4, 8), 256, 0, stream>>>(p); }
  softmax_rows_bf16_256<<<512, 256, 0, stream>>>(x2);

  // 5+6) pinv — depth-2 coupled iteration (R2-validated):
  prescale<<<16, 256, 0, stream>>>(x2, sbuf);
  pinv_init<<<dim3(16, 8), 256, 0, stream>>>(x2, sbuf, z0, z0T);
  { PG p{x2, z0T, nullptr, nullptr, Amat, AmatT, 1.f, 0.f};
    pinv_gemm<true, true><<<dim3(4, 4, 8), 256, 0, stream>>>(p); }
  {
    const dim3 b(256);
    u16 *zr = z0, *zo = zp;
    u16 *Ar = Amat, *Art = AmatT, *Ao = Am2, *Aot = Am2T;
    for (int it = 0; it < 6; it++) {
      { PR1 r{Ar, Art, zr, Bm, BmT, Gm, GmT, Wm};
        pinv_r1<<<dim3(4, 4, 16), b, 0, stream>>>(r); }
      { PR2 r{Wm, Gm, GmT, Bm, BmT, zr, Ar, Art, zo, Ao, Aot};
        pinv_r2<<<dim3(4, 4, (it == 5) ? 8 : 16), b, 0, stream>>>(r); }
      u16* t;
      t = zr; zr = zo; zo = t;
      t = Ar; Ar = Ao; Ao = t;
      t = Art; Art = Aot; Aot = t;
    }
  }
  // final z row-major in z0 (6 swaps -> zr == z0)

  // 7+8) av = softmax(q_l @ k^T) @ v — fully fused, split-K 32 (2 blocks/CU).
  { AVF p{qkvb, ql, vT, avp, denp};
    av_fused<<<dim3(1, 2, 256), 256, 0, stream>>>(p); }
  reduce_avT<<<512, 256, 0, stream>>>(avp, denp, avT);

  // 9) MmT = (pinv @ av)^T
  { MP p = mp(z0, avT, 256, 64, 256, 256, 256, 65536, 16384);
    p.Ct = MmT; p.ldct = 256; p.bCt = 16384;
    gemm_mfma<64, 64, false><<<dim3(1, 4, 8), 256, 0, stream>>>(p); }

  // 10+11) af = softmax(q @ k_l^T) @ Mm — fused (staged GLL form, proven)
  { FA1 fp{qkvb, kl, MmT, af};
    fused_attn1<<<dim3(128, 8), 256, 0, stream>>>(fp); }

  // 12) af += depthwise conv(v) — standalone (proven layout)
  conv_res_add_bf16<<<dim3(128, 8), 256, 0, stream>>>(qkvb, conv_w, af);

  // 13) score partials: split-K x4, per-chunk row-dot with W_score in the
  // epilogue — af_out never materialized.
  { MP p = mp(af, WoutT, 8192, 256, 128, 512, 512, 0, 0);
    p.kchunks = 4; p.Ws = W_score; p.sc = scores;
    gemm_mfma<64, 256, false><<<dim3(1, 128, 4), 256, 0, stream>>>(p); }

  // 14+15+16) combine partials + wconst + relu -> softmax -> aggregate
  // (9 blocks: 8 column-group aggregated blocks + 1 weights block)
  fused_tail<<<9, 256, 0, stream>>>(scores, wconst, hb, out);
}

// Round 14
// 315.165 us; speedup vs baseline: 1.2383x; 1.2383x over previous
//
#include <hip/hip_runtime.h>

typedef unsigned short u16;
typedef __attribute__((ext_vector_type(8))) short s16x8;
typedef __attribute__((ext_vector_type(4))) float f32x4;
typedef __attribute__((ext_vector_type(8))) unsigned short u16x8;

__device__ inline float b2f(u16 u) {
  unsigned x = ((unsigned)u) << 16;
  return __builtin_bit_cast(float, x);
}
__device__ inline u16 f2b(float f) {
  unsigned u = __builtin_bit_cast(unsigned, f);
  u += 0x7fffu + ((u >> 16) & 1u);
  return (u16)(u >> 16);
}

#define GLL(src, dst) __builtin_amdgcn_global_load_lds( \
    (const __attribute__((address_space(1))) unsigned int*)(src), \
    (__attribute__((address_space(3))) unsigned int*)(dst), 16, 0, 0)

// ---------------------------------------------------------------------------
// Batched MFMA GEMM (proven): C = alpha*(A @ B^T) + beta*Aadd + bias.
// Score mode (Ws != null, BN==256): per-chunk epilogue writes PARTIAL row-dot
//   sc[bz*8192 + row] = sum_c acc[row][c]*Ws[c]   (combined in fused_tail).
// ---------------------------------------------------------------------------
struct MP {
  const u16* A; const u16* B;
  u16* C; u16* Ct; float* Cf; u16* vTo;
  const u16* Aadd; const float* bias;
  const float* Ws; float* sc;
  int M, N, K;
  int lda, ldb, ldc, ldct, ldcf, ldaadd;
  long long bA, bB, bC, bCt, bCf, bAadd;
  float alpha, beta;
  int relu, scale_cols; float colscale;
  int kchunks;
};

template<int BM, int BN, bool F32A>
__global__ __launch_bounds__(256) void gemm_mfma(MP p)
{
  constexpr int WM = BM / 2, WN = BN / 2;
  constexpr int FM = WM / 16, FN = WN / 16;
  constexpr int APAN = BM / 16, BPAN = BN / 16, NPAN = APAN + BPAN;
  constexpr int APW = (APAN + 3) / 4;
  __shared__ __align__(16) u16 lds[2 * NPAN * 512];

  const int tid = threadIdx.x, lane = tid & 63, wid = tid >> 6;
  const int bz = blockIdx.z;
  const int batch = (p.kchunks > 1) ? bz / p.kchunks : bz;
  const int kc    = (p.kchunks > 1) ? bz % p.kchunks : 0;
  const u16* A = p.A + (long long)batch * p.bA + (long long)kc * p.K;
  const float* Af32 = (const float*)p.A + (long long)batch * p.bA + (long long)kc * p.K;
  const u16* B = p.B + (long long)batch * p.bB + (long long)kc * p.K;
  const int m0 = blockIdx.y * BM, n0 = blockIdx.x * BN;
  const int srow = lane & 15, skoff = (lane >> 4) * 8;
  const int wm0 = (wid >> 1) * WM, wn0 = (wid & 1) * WN;

  f32x4 acc[FM][FN];
#pragma unroll
  for (int i = 0; i < FM; i++)
#pragma unroll
    for (int j = 0; j < FN; j++) acc[i][j] = (f32x4){0.f, 0.f, 0.f, 0.f};

  float4 areg[APW][2];

  auto stage_all = [&](int sb, int kt) {
#pragma unroll
    for (int pp = wid; pp < NPAN; pp += 4) {
      const u16* src = (pp < APAN)
        ? A + (size_t)(m0 + pp * 16 + srow) * p.lda + kt + skoff
        : B + (size_t)(n0 + (pp - APAN) * 16 + srow) * p.ldb + kt + skoff;
      GLL(src, &lds[sb * (NPAN * 512) + pp * 512]);
    }
  };
  auto stage_b = [&](int sb, int kt) {
#pragma unroll
    for (int pp = APAN + wid; pp < NPAN; pp += 4) {
      const u16* src = B + (size_t)(n0 + (pp - APAN) * 16 + srow) * p.ldb + kt + skoff;
      GLL(src, &lds[sb * (NPAN * 512) + pp * 512]);
    }
  };
  auto load_a = [&](int kt) {
#pragma unroll
    for (int ap = 0; ap < APW; ap++) {
      int pp = wid + ap * 4;
      const float* src = Af32 + (size_t)(m0 + pp * 16 + srow) * p.lda + kt + skoff;
      areg[ap][0] = ((const float4*)src)[0];
      areg[ap][1] = ((const float4*)src)[1];
    }
  };
  auto write_a = [&](int sb) {
#pragma unroll
    for (int ap = 0; ap < APW; ap++) {
      int pp = wid + ap * 4;
      u16 t[8];
      t[0] = f2b(areg[ap][0].x); t[1] = f2b(areg[ap][0].y);
      t[2] = f2b(areg[ap][0].z); t[3] = f2b(areg[ap][0].w);
      t[4] = f2b(areg[ap][1].x); t[5] = f2b(areg[ap][1].y);
      t[6] = f2b(areg[ap][1].z); t[7] = f2b(areg[ap][1].w);
      *(s16x8*)&lds[sb * (NPAN * 512) + pp * 512 + lane * 8] = *(const s16x8*)t;
    }
  };
  auto compute = [&](int sb) {
    const int bo = sb * (NPAN * 512);
    s16x8 afr[FM], bfr[FN];
#pragma unroll
    for (int i = 0; i < FM; i++)
      afr[i] = *(const s16x8*)&lds[bo + (wm0 / 16 + i) * 512 + lane * 8];
#pragma unroll
    for (int j = 0; j < FN; j++)
      bfr[j] = *(const s16x8*)&lds[bo + (APAN + wn0 / 16 + j) * 512 + lane * 8];
#pragma unroll
    for (int i = 0; i < FM; i++)
#pragma unroll
      for (int j = 0; j < FN; j++)
        acc[i][j] = __builtin_amdgcn_mfma_f32_16x16x32_bf16(afr[i], bfr[j], acc[i][j], 0, 0, 0);
  };

  const int nt = p.K / 32;
  int buf = 0;
  if constexpr (F32A) { load_a(0); stage_b(0, 0); write_a(0); }
  else                { stage_all(0, 0); }
  asm volatile("s_waitcnt vmcnt(0)" ::: "memory");
  __syncthreads();

  for (int t = 0; t < nt; ++t) {
    if constexpr (F32A) {
      if (t + 1 < nt) { load_a((t + 1) * 32); stage_b(buf ^ 1, (t + 1) * 32); }
      compute(buf);
      if (t + 1 < nt) write_a(buf ^ 1);
    } else {
      if (t + 1 < nt) stage_all(buf ^ 1, (t + 1) * 32);
      compute(buf);
    }
    asm volatile("s_waitcnt vmcnt(0)" ::: "memory");
    __syncthreads();
    buf ^= 1;
  }

  const int r0 = (lane >> 4) * 4, c0 = lane & 15;

  if (p.Ws) {
    // Partial score epilogue: per-row dot with Ws (no bias/relu — linear in K,
    // so split-K partials sum exactly; fused_tail combines + relu).
    float* sb = (float*)lds;   // [2 col-halves][64 rows]; safe after last sync
#pragma unroll
    for (int i = 0; i < FM; i++)
#pragma unroll
      for (int q = 0; q < 4; q++) {
        float s = 0.f;
#pragma unroll
        for (int j = 0; j < FN; j++)
          s += acc[i][j][q] * p.Ws[wn0 + j * 16 + c0];
        s += __shfl_xor(s, 1); s += __shfl_xor(s, 2);
        s += __shfl_xor(s, 4); s += __shfl_xor(s, 8);
        if ((lane & 15) == 0) sb[(wid & 1) * 64 + wm0 + i * 16 + r0 + q] = s;
      }
    __syncthreads();
    if (tid < 64)
      p.sc[(size_t)bz * 8192 + m0 + tid] = sb[tid] + sb[64 + tid];
    return;
  }

#pragma unroll
  for (int i = 0; i < FM; i++) {
#pragma unroll
    for (int j = 0; j < FN; j++) {
#pragma unroll
      for (int q = 0; q < 4; q++) {
        const int gr = m0 + wm0 + i * 16 + r0 + q;
        const int gc = n0 + wn0 + j * 16 + c0;
        float c = p.alpha * acc[i][j][q];
        if (p.Aadd) c += p.beta * b2f(p.Aadd[(long long)batch * p.bAadd + (size_t)gr * p.ldaadd + gc]);
        if (p.bias) c += p.bias[gc];
        if (gc < p.scale_cols) c *= p.colscale;
        if (p.relu) c = fmaxf(c, 0.f);
        if (p.Cf) p.Cf[(long long)bz * p.bCf + (size_t)gr * p.ldcf + gc] = c;
        u16 b = f2b(c);
        if (p.C)  p.C [(long long)batch * p.bC + (size_t)gr * p.ldc + gc] = b;
        if (p.Ct) p.Ct[(long long)batch * p.bCt + (size_t)gc * p.ldct + gr] = b;
        if (p.vTo && gc >= 1024) p.vTo[(size_t)(gc - 1024) * 8192 + gr] = b;
      }
    }
  }
}

// ---------------------------------------------------------------------------
// reduce_bias_bf16: sum 4 split-K f32 partials + bias + relu -> bf16.
// ---------------------------------------------------------------------------
__global__ void reduce_bias_bf16(const float* __restrict__ parts,
                                 const float* __restrict__ bias,
                                 u16* __restrict__ out)
{
  const int i4 = blockIdx.x * 256 + threadIdx.x;
  float4 s = ((const float4*)parts)[i4];
#pragma unroll
  for (int k = 1; k < 4; k++) {
    float4 v = ((const float4*)parts)[(size_t)k * 524288 + i4];
    s.x += v.x; s.y += v.y; s.z += v.z; s.w += v.w;
  }
  const float4 b = ((const float4*)bias)[i4 & 63];
  s.x = fmaxf(s.x + b.x, 0.f); s.y = fmaxf(s.y + b.y, 0.f);
  s.z = fmaxf(s.z + b.z, 0.f); s.w = fmaxf(s.w + b.w, 0.f);
  ushort4 o; o.x = f2b(s.x); o.y = f2b(s.y); o.z = f2b(s.z); o.w = f2b(s.w);
  ((ushort4*)out)[i4] = o;
}

// ---------------------------------------------------------------------------
// av_fused: softmax(q_l @ k^T) @ v without materializing S. Split-K 32
// (512 blocks = 2/CU for latency hiding; nt=8 serial phases per block).
// ---------------------------------------------------------------------------
struct AVF { const u16 *qkvb, *ql, *vT; float *Cf, *den; };

__global__ __launch_bounds__(256) void av_fused(AVF p)
{
  __shared__ __align__(16) u16 lds[20480];
  const int tid = threadIdx.x, lane = tid & 63, wid = tid >> 6;
  const int bz = blockIdx.z, head = bz >> 5, kc = bz & 31;
  const int m0 = blockIdx.y * 128;
  const int srow = lane & 15, skoff = (lane >> 4) * 8;
  const int r0 = (lane >> 4) * 4, c0 = lane & 15;
  const u16* Kb = p.qkvb + 512 + (size_t)(kc * 256) * 1536 + head * 64;
  const u16* Vb = p.vT + (size_t)head * 524288 + kc * 256;
  const u16* QL = p.ql + head * 16384 + (size_t)m0 * 64;

#pragma unroll
  for (int q = 0; q < 4; q++) {
    int pid = wid * 4 + q, pr = pid >> 1, kc2 = pid & 1;
    GLL(QL + (size_t)(pr * 16 + srow) * 64 + kc2 * 32 + skoff, &lds[pid * 512]);
  }
  auto stage_kv = [&](int sb, int t) {
    int kr = wid >> 1, kc2 = wid & 1;
    GLL(Kb + (size_t)(t * 32 + kr * 16 + srow) * 1536 + kc2 * 32 + skoff,
        &lds[8192 + sb * 2048 + wid * 512]);
    GLL(Vb + (size_t)(wid * 16 + srow) * 8192 + t * 32 + skoff,
        &lds[12288 + sb * 2048 + wid * 512]);
  };

  f32x4 acc[4][2];
#pragma unroll
  for (int i = 0; i < 4; i++)
#pragma unroll
    for (int j = 0; j < 2; j++) acc[i][j] = (f32x4){0.f, 0.f, 0.f, 0.f};
  float den[2][4];
#pragma unroll
  for (int i = 0; i < 2; i++)
#pragma unroll
    for (int q = 0; q < 4; q++) den[i][q] = 0.f;

  const int nt = 8;
  int buf = 0;
  stage_kv(0, 0);
  asm volatile("s_waitcnt vmcnt(0)" ::: "memory");
  __syncthreads();

  for (int t = 0; t < nt; ++t) {
    if (t + 1 < nt) stage_kv(buf ^ 1, t + 1);
    f32x4 s[2][2];
#pragma unroll
    for (int i = 0; i < 2; i++)
#pragma unroll
      for (int j = 0; j < 2; j++) s[i][j] = (f32x4){0.f, 0.f, 0.f, 0.f};
#pragma unroll
    for (int t2 = 0; t2 < 2; t2++) {
      s16x8 aq[2], bk[2];
#pragma unroll
      for (int i = 0; i < 2; i++)
        aq[i] = *(const s16x8*)&lds[((wid * 2 + i) * 2 + t2) * 512 + lane * 8];
#pragma unroll
      for (int j = 0; j < 2; j++)
        bk[j] = *(const s16x8*)&lds[8192 + buf * 2048 + (j * 2 + t2) * 512 + lane * 8];
#pragma unroll
      for (int i = 0; i < 2; i++)
#pragma unroll
        for (int j = 0; j < 2; j++)
          s[i][j] = __builtin_amdgcn_mfma_f32_16x16x32_bf16(aq[i], bk[j], s[i][j], 0, 0, 0);
    }
#pragma unroll
    for (int i = 0; i < 2; i++)
#pragma unroll
      for (int j = 0; j < 2; j++)
#pragma unroll
        for (int q = 0; q < 4; q++) {
          float e = expf(s[i][j][q]);
          den[i][q] += e;
          int kk = j * 16 + c0;
          lds[16384 + (wid * 2 + i) * 512 + (r0 + q) * 8 + (kk >> 3) * 128 + (kk & 7)] = f2b(e);
        }
    asm volatile("s_waitcnt vmcnt(0)" ::: "memory");
    __syncthreads();
    {
      s16x8 afr[4], bfr[2];
#pragma unroll
      for (int i = 0; i < 4; i++)
        afr[i] = *(const s16x8*)&lds[16384 + ((wid >> 1) * 4 + i) * 512 + lane * 8];
#pragma unroll
      for (int j = 0; j < 2; j++)
        bfr[j] = *(const s16x8*)&lds[12288 + buf * 2048 + ((wid & 1) * 2 + j) * 512 + lane * 8];
#pragma unroll
      for (int i = 0; i < 4; i++)
#pragma unroll
        for (int j = 0; j < 2; j++)
          acc[i][j] = __builtin_amdgcn_mfma_f32_16x16x32_bf16(afr[i], bfr[j], acc[i][j], 0, 0, 0);
    }
    __syncthreads();
    buf ^= 1;
  }

#pragma unroll
  for (int i = 0; i < 4; i++)
#pragma unroll
    for (int j = 0; j < 2; j++)
#pragma unroll
      for (int q = 0; q < 4; q++) {
        const int gr = m0 + (wid >> 1) * 64 + i * 16 + r0 + q;
        const int gc = (wid & 1) * 32 + j * 16 + c0;
        p.Cf[(size_t)bz * 16384 + (size_t)gr * 64 + gc] = acc[i][j][q];
      }
#pragma unroll
  for (int i = 0; i < 2; i++)
#pragma unroll
    for (int q = 0; q < 4; q++) {
      float v = den[i][q];
      v += __shfl_xor(v, 1); v += __shfl_xor(v, 2);
      v += __shfl_xor(v, 4); v += __shfl_xor(v, 8);
      if (c0 == 0)
        p.den[(size_t)bz * 256 + m0 + wid * 32 + i * 16 + r0 + q] = v;
    }
}

// ---------------------------------------------------------------------------
// fused_attn1 (r11-validated form, NO conv): af = softmax(q @ k_l^T) @ Mm.
// ---------------------------------------------------------------------------
struct FA1 { const u16 *qkvb, *kl, *MmT; u16 *af; };

__global__ __launch_bounds__(256) void fused_attn1(FA1 p)
{
  __shared__ __align__(16) u16 lds[36864];
  __shared__ float mb[4][64];
  const int tid = threadIdx.x, lane = tid & 63, wid = tid >> 6;
  const int head = blockIdx.y, n0 = blockIdx.x * 64;
  const int srow = lane & 15, skoff = (lane >> 4) * 8;
  const int rbase = (lane >> 4) * 4;

  for (int pid = wid; pid < 72; pid += 4) {
    const u16* src;
    if (pid < 8) {
      int pr = pid >> 1, kc = pid & 1;
      src = p.qkvb + (size_t)(n0 + pr * 16 + srow) * 1536 + head * 64 + kc * 32 + skoff;
    } else if (pid < 40) {
      int j = pid - 8, pr = j >> 1, kc = j & 1;
      src = p.kl + head * 16384 + (size_t)(pr * 16 + srow) * 64 + kc * 32 + skoff;
    } else {
      int j = pid - 40, pr = j >> 3, kc = j & 7;
      src = p.MmT + head * 16384 + (size_t)(pr * 16 + srow) * 256 + kc * 32 + skoff;
    }
    GLL(src, &lds[pid * 512]);
  }
  asm volatile("s_waitcnt vmcnt(0)" ::: "memory");
  __syncthreads();

  const int wr = (wid >> 1) * 32, ch_ = wid & 1;
  f32x4 s[2][8];
#pragma unroll
  for (int i = 0; i < 2; i++)
#pragma unroll
    for (int j = 0; j < 8; j++) s[i][j] = (f32x4){0.f, 0.f, 0.f, 0.f};
#pragma unroll
  for (int t = 0; t < 2; t++) {
    s16x8 a[2], b[8];
#pragma unroll
    for (int i = 0; i < 2; i++)
      a[i] = *(const s16x8*)&lds[(((wid >> 1) * 2 + i) * 2 + t) * 512 + lane * 8];
#pragma unroll
    for (int j = 0; j < 8; j++)
      b[j] = *(const s16x8*)&lds[4096 + ((ch_ * 8 + j) * 2 + t) * 512 + lane * 8];
#pragma unroll
    for (int i = 0; i < 2; i++)
#pragma unroll
      for (int j = 0; j < 8; j++)
        s[i][j] = __builtin_amdgcn_mfma_f32_16x16x32_bf16(a[i], b[j], s[i][j], 0, 0, 0);
  }
#pragma unroll
  for (int i = 0; i < 2; i++)
#pragma unroll
    for (int q = 0; q < 4; q++) {
      float rm = -INFINITY;
#pragma unroll
      for (int j = 0; j < 8; j++) rm = fmaxf(rm, s[i][j][q]);
#pragma unroll
      for (int off = 1; off < 16; off <<= 1) rm = fmaxf(rm, __shfl_xor(rm, off));
      if ((lane & 15) == 0) mb[ch_][wr + i * 16 + rbase + q] = rm;
    }
  __syncthreads();
  float m_[2][4];
#pragma unroll
  for (int i = 0; i < 2; i++)
#pragma unroll
    for (int q = 0; q < 4; q++)
      m_[i][q] = fmaxf(mb[0][wr + i * 16 + rbase + q], mb[1][wr + i * 16 + rbase + q]);
#pragma unroll
  for (int i = 0; i < 2; i++)
#pragma unroll
    for (int q = 0; q < 4; q++) {
      float ss = 0.f;
#pragma unroll
      for (int j = 0; j < 8; j++) {
        float e = expf(s[i][j][q] - m_[i][q]);
        s[i][j][q] = e; ss += e;
      }
#pragma unroll
      for (int off = 1; off < 16; off <<= 1) ss += __shfl_xor(ss, off);
      if ((lane & 15) == 0) mb[2 + ch_][wr + i * 16 + rbase + q] = ss;
    }
  __syncthreads();
#pragma unroll
  for (int i = 0; i < 2; i++)
#pragma unroll
    for (int q = 0; q < 4; q++) {
      int row = wr + i * 16 + rbase + q;
      float inv = 1.f / (mb[2][row] + mb[3][row]);
#pragma unroll
      for (int j = 0; j < 8; j++)
        lds[(size_t)row * 264 + ch_ * 128 + j * 16 + (lane & 15)] = f2b(s[i][j][q] * inv);
    }
  __syncthreads();
  const int wr2 = (wid >> 1) * 32, wd2 = (wid & 1) * 32;
  f32x4 acc[2][2];
#pragma unroll
  for (int i = 0; i < 2; i++)
#pragma unroll
    for (int jd = 0; jd < 2; jd++) acc[i][jd] = (f32x4){0.f, 0.f, 0.f, 0.f};
#pragma unroll
  for (int t = 0; t < 8; t++) {
    s16x8 a[2], b[2];
#pragma unroll
    for (int i = 0; i < 2; i++)
      a[i] = *(const s16x8*)&lds[(size_t)(wr2 + i * 16 + (lane & 15)) * 264 + t * 32 + (lane >> 4) * 8];
#pragma unroll
    for (int jd = 0; jd < 2; jd++)
      b[jd] = *(const s16x8*)&lds[20480 + (((wid & 1) * 2 + jd) * 8 + t) * 512 + lane * 8];
#pragma unroll
    for (int i = 0; i < 2; i++)
#pragma unroll
      for (int jd = 0; jd < 2; jd++)
        acc[i][jd] = __builtin_amdgcn_mfma_f32_16x16x32_bf16(a[i], b[jd], acc[i][jd], 0, 0, 0);
  }
#pragma unroll
  for (int i = 0; i < 2; i++)
#pragma unroll
    for (int jd = 0; jd < 2; jd++)
#pragma unroll
      for (int q = 0; q < 4; q++)
        p.af[(size_t)(n0 + wr2 + i * 16 + rbase + q) * 512 + head * 64 + wd2 + jd * 16 + (lane & 15)]
            = f2b(acc[i][jd][q]);
}

// ---------------------------------------------------------------------------
// conv_res_add_bf16 (proven standalone; wave = 64 consecutive ch in one row)
// ---------------------------------------------------------------------------
__global__ void conv_res_add_bf16(const u16* __restrict__ qkvb,
                                  const float* __restrict__ convw,
                                  u16* __restrict__ af)
{
  __shared__ float vt[96][64];
  const int h = blockIdx.y, n0 = blockIdx.x * 64;
  const int t = threadIdx.x, ch = t & 63, r0 = t >> 6;
  for (int r = r0; r < 96; r += 4) {
    int n = n0 - 16 + r;
    float v = 0.f;
    if (n >= 0 && n < 8192) v = b2f(qkvb[(size_t)n * 1536 + 1024 + h * 64 + ch]);
    vt[r][ch] = v;
  }
  __syncthreads();
  float w[33];
#pragma unroll
  for (int j = 0; j < 33; j++) w[j] = convw[h * 33 + j];
  for (int tl = r0; tl < 64; tl += 4) {
    float acc = 0.f;
#pragma unroll
    for (int j = 0; j < 33; j++) acc += w[j] * vt[tl + j][ch];
    size_t o = (size_t)(n0 + tl) * 512 + h * 64 + ch;
    af[o] = f2b(b2f(af[o]) + acc);
  }
}

// ---------------------------------------------------------------------------
// fused_tail (R12-validated 257-block form): combine split-K score partials
// (+wconst, relu), softmax -> weights (out[256..]) and aggregated = w @ h.
// (R13's 9-block coalesced variant was latency-bound at 0.33% occupancy —
//  92us. Occupancy >> coalescing for this reduction.)
// ---------------------------------------------------------------------------
__global__ void fused_tail(const float* __restrict__ sp,
                           const float* __restrict__ wconst,
                           const u16* __restrict__ hb, float* __restrict__ out)
{
  __shared__ float red[256];
  const int t = threadIdx.x, c = blockIdx.x;
  const float wc = wconst[0];
  float e[32];
  float m = -INFINITY;
#pragma unroll
  for (int i = 0; i < 32; i++) {
    int idx = t + i * 256;
    float v = sp[idx] + sp[8192 + idx] + sp[16384 + idx] + sp[24576 + idx] + wc;
    v = fmaxf(v, 0.f);
    e[i] = v; m = fmaxf(m, v);
  }
  red[t] = m; __syncthreads();
  for (int s = 128; s; s >>= 1) { if (t < s) red[t] = fmaxf(red[t], red[t + s]); __syncthreads(); }
  m = red[0]; __syncthreads();
  float ls = 0.f;
#pragma unroll
  for (int i = 0; i < 32; i++) { e[i] = expf(e[i] - m); ls += e[i]; }
  red[t] = ls; __syncthreads();
  for (int s = 128; s; s >>= 1) { if (t < s) red[t] += red[t + s]; __syncthreads(); }
  const float inv = 1.f / red[0];
  __syncthreads();

  if (c < 256) {
    float acc = 0.f;
#pragma unroll
    for (int i = 0; i < 32; i++)
      acc += e[i] * inv * b2f(hb[(size_t)(t + i * 256) * 256 + c]);
    red[t] = acc; __syncthreads();
    for (int s = 128; s; s >>= 1) { if (t < s) red[t] += red[t + s]; __syncthreads(); }
    if (t == 0) out[c] = red[0];
  } else {
#pragma unroll
    for (int i = 0; i < 32; i++) out[256 + t + i * 256] = e[i] * inv;
  }
}

// ---------------------------------------------------------------------------
// prescale: 16 blocks — blocks 0..7 row-abs-sum max (rs), 8..15 col (cs).
// ---------------------------------------------------------------------------
__global__ void prescale(const u16* __restrict__ x2, float* __restrict__ sbuf)
{
  const int h = blockIdx.x & 7, which = blockIdx.x >> 3, t = threadIdx.x;
  const u16* X = x2 + ((size_t)h << 16);
  __shared__ float red[256];
  float s = 0.f;
  if (which == 0) {
    for (int c4 = 0; c4 < 256; c4 += 4) {
      ushort4 v = *(const ushort4*)(X + (size_t)t * 256 + c4);
      s += fabsf(b2f(v.x)) + fabsf(b2f(v.y)) + fabsf(b2f(v.z)) + fabsf(b2f(v.w));
    }
  } else {
    for (int r = 0; r < 256; r++) s += fabsf(b2f(X[r * 256 + t]));
  }
  red[t] = s; __syncthreads();
  for (int st = 128; st; st >>= 1) {
    if (t < st) red[t] = fmaxf(red[t], red[t + st]);
    __syncthreads();
  }
  if (t == 0) sbuf[which * 8 + h] = red[0];
}

__global__ void pinv_init(const u16* __restrict__ x2, const float* __restrict__ sbuf,
                          u16* __restrict__ z0, u16* __restrict__ z0T)
{
  __shared__ u16 tile[64][80];
  const int t = threadIdx.x;
  const size_t base = (size_t)blockIdx.y << 16;
  const int tr = (blockIdx.x >> 2) * 64, tc = (blockIdx.x & 3) * 64;
  const u16* X = x2 + base;

  float mr = -INFINITY, mc = -INFINITY;
#pragma unroll
  for (int i = 0; i < 8; i++) {
    mr = fmaxf(mr, sbuf[i]);
    mc = fmaxf(mc, sbuf[8 + i]);
  }
  const float inv = 1.f / (mr * mc);

  {
    int r = t >> 2, cg = (t & 3) * 16;
#pragma unroll
    for (int v4 = 0; v4 < 4; v4++) {
      ushort4 v = *(const ushort4*)(X + (size_t)(tr + r) * 256 + tc + cg + v4 * 4);
      v.x = f2b(b2f(v.x) * inv); v.y = f2b(b2f(v.y) * inv);
      v.z = f2b(b2f(v.z) * inv); v.w = f2b(b2f(v.w) * inv);
      *(ushort4*)(z0T + base + (size_t)(tr + r) * 256 + tc + cg + v4 * 4) = v;
      *(ushort4*)&tile[r][cg + v4 * 4] = v;
    }
  }
  __syncthreads();
  {
    int c = t >> 2, rg = (t & 3) * 16;
    u16 o[16];
#pragma unroll
    for (int e = 0; e < 16; e++) o[e] = tile[rg + e][c];
#pragma unroll
    for (int v4 = 0; v4 < 4; v4++)
      *(ushort4*)(z0 + base + (size_t)(tc + c) * 256 + tr + rg + v4 * 4) = *(ushort4*)&o[v4 * 4];
  }
}

// ---------------------------------------------------------------------------
// pinv_gemm: kept for the one-time A0 = x2 @ z0 (writes A0 and A0^T).
// ---------------------------------------------------------------------------
struct PG {
  const u16 *U, *V, *Xadd, *XaddT;
  u16 *DR, *DT;
  float alpha, beta;
};

template<bool WD, bool WDT>
__global__ __launch_bounds__(256) void pinv_gemm(PG p)
{
  __shared__ __align__(16) u16 lds[65536 / 2];
  const int tid = threadIdx.x, lane = tid & 63, wid = tid >> 6;
  const size_t base = (size_t)blockIdx.z << 16;
  const u16* U = p.U + base;
  const u16* V = p.V + base;
  const int m0 = blockIdx.y * 64, n0 = blockIdx.x * 64;
  const int srow = lane & 15, skoff = (lane >> 4) * 8;
  const int wr = (wid >> 1) * 32, wc = (wid & 1) * 32;

#pragma unroll
  for (int q = 0; q < 16; q++) {
    const int pid = wid * 16 + q;
    const int rg = (pid >> 3) & 3, t = pid & 7;
    const u16* src = (pid < 32)
      ? U + (size_t)(m0 + rg * 16 + srow) * 256 + t * 32 + skoff
      : V + (size_t)(n0 + rg * 16 + srow) * 256 + t * 32 + skoff;
    GLL(src, &lds[pid * 512]);
  }
  asm volatile("s_waitcnt vmcnt(0)" ::: "memory");
  __syncthreads();

  f32x4 acc[2][2], accT[2][2];
#pragma unroll
  for (int i = 0; i < 2; i++)
#pragma unroll
    for (int j = 0; j < 2; j++) {
      acc[i][j] = (f32x4){0.f, 0.f, 0.f, 0.f};
      accT[i][j] = (f32x4){0.f, 0.f, 0.f, 0.f};
    }

#pragma unroll
  for (int t = 0; t < 8; t++) {
    s16x8 afr[2], bfr[2];
#pragma unroll
    for (int i = 0; i < 2; i++)
      afr[i] = *(const s16x8*)&lds[((wr / 16 + i) * 8 + t) * 512 + lane * 8];
#pragma unroll
    for (int j = 0; j < 2; j++)
      bfr[j] = *(const s16x8*)&lds[(32 + (wc / 16 + j) * 8 + t) * 512 + lane * 8];
#pragma unroll
    for (int i = 0; i < 2; i++)
#pragma unroll
      for (int j = 0; j < 2; j++) {
        if constexpr (WD)
          acc[i][j] = __builtin_amdgcn_mfma_f32_16x16x32_bf16(afr[i], bfr[j], acc[i][j], 0, 0, 0);
        if constexpr (WDT)
          accT[j][i] = __builtin_amdgcn_mfma_f32_16x16x32_bf16(bfr[j], afr[i], accT[j][i], 0, 0, 0);
      }
  }

  const int r0 = (lane >> 4) * 4, c0 = lane & 15;
  if constexpr (WD) {
    const u16* Xa = p.Xadd ? p.Xadd + base : nullptr;
    u16* DR = p.DR + base;
#pragma unroll
    for (int i = 0; i < 2; i++)
#pragma unroll
      for (int j = 0; j < 2; j++)
#pragma unroll
        for (int q = 0; q < 4; q++) {
          const int gr = m0 + wr + i * 16 + r0 + q;
          const int gc = n0 + wc + j * 16 + c0;
          float v = p.alpha * acc[i][j][q];
          if (Xa) v += p.beta * b2f(Xa[(size_t)gr * 256 + gc]);
          DR[(size_t)gr * 256 + gc] = f2b(v);
        }
  }
  if constexpr (WDT) {
    const u16* Xt = p.XaddT ? p.XaddT + base : nullptr;
    u16* DT = p.DT + base;
#pragma unroll
    for (int j = 0; j < 2; j++)
#pragma unroll
      for (int i = 0; i < 2; i++)
#pragma unroll
        for (int q = 0; q < 4; q++) {
          const int gn = n0 + wc + j * 16 + r0 + q;
          const int gm = m0 + wr + i * 16 + c0;
          float v = p.alpha * accT[j][i][q];
          if (Xt) v += p.beta * b2f(Xt[(size_t)gn * 256 + gm]);
          DT[(size_t)gn * 256 + gm] = f2b(v);
        }
  }
}

// ---------------------------------------------------------------------------
// Depth-2 pinv iteration (coupled A,z form; A = x@z invariant):
//   B = A@A, G = 7A - B, W = z@A
//   z' = 0.25*(W@G) + 3.25*z - 3.75*W
//   A' = 0.25*(G@B) + 3.25*A - 3.75*B      ( = x@z' in exact arithmetic )
// ---------------------------------------------------------------------------
struct PR1 { const u16 *A, *At, *z; u16 *B, *Bt, *G, *Gt, *W; };

__global__ __launch_bounds__(256) void pinv_r1(PR1 p)
{
  __shared__ __align__(16) u16 lds[32768];
  const int tid = threadIdx.x, lane = tid & 63, wid = tid >> 6;
  const int prob = blockIdx.z >> 3;
  const size_t base = (size_t)(blockIdx.z & 7) << 16;
  const u16* U = (prob ? p.z : p.A) + base;
  const u16* V = p.At + base;
  const int m0 = blockIdx.y * 64, n0 = blockIdx.x * 64;
  const int srow = lane & 15, skoff = (lane >> 4) * 8;
  const int wr = (wid >> 1) * 32, wc = (wid & 1) * 32;

#pragma unroll
  for (int q = 0; q < 16; q++) {
    const int pid = wid * 16 + q;
    const int rg = (pid >> 3) & 3, t = pid & 7;
    const u16* src = (pid < 32)
      ? U + (size_t)(m0 + rg * 16 + srow) * 256 + t * 32 + skoff
      : V + (size_t)(n0 + rg * 16 + srow) * 256 + t * 32 + skoff;
    GLL(src, &lds[pid * 512]);
  }
  asm volatile("s_waitcnt vmcnt(0)" ::: "memory");
  __syncthreads();

  f32x4 acc[2][2], accT[2][2];
#pragma unroll
  for (int i = 0; i < 2; i++)
#pragma unroll
    for (int j = 0; j < 2; j++) {
      acc[i][j] = (f32x4){0.f, 0.f, 0.f, 0.f};
      accT[i][j] = (f32x4){0.f, 0.f, 0.f, 0.f};
    }

#pragma unroll
  for (int t = 0; t < 8; t++) {
    s16x8 afr[2], bfr[2];
#pragma unroll
    for (int i = 0; i < 2; i++)
      afr[i] = *(const s16x8*)&lds[((wr / 16 + i) * 8 + t) * 512 + lane * 8];
#pragma unroll
    for (int j = 0; j < 2; j++)
      bfr[j] = *(const s16x8*)&lds[(32 + (wc / 16 + j) * 8 + t) * 512 + lane * 8];
#pragma unroll
    for (int i = 0; i < 2; i++)
#pragma unroll
      for (int j = 0; j < 2; j++) {
        acc[i][j] = __builtin_amdgcn_mfma_f32_16x16x32_bf16(afr[i], bfr[j], acc[i][j], 0, 0, 0);
        if (prob == 0)
          accT[j][i] = __builtin_amdgcn_mfma_f32_16x16x32_bf16(bfr[j], afr[i], accT[j][i], 0, 0, 0);
      }
  }

  const int r0 = (lane >> 4) * 4, c0 = lane & 15;
  if (prob == 0) {
    const u16* Ab  = p.A  + base;
    const u16* Atb = p.At + base;
    u16 *Bv = p.B + base, *Btv = p.Bt + base;
    u16 *Gv = p.G + base, *Gtv = p.Gt + base;
#pragma unroll
    for (int i = 0; i < 2; i++)
#pragma unroll
      for (int j = 0; j < 2; j++)
#pragma unroll
        for (int q = 0; q < 4; q++) {
          const int gr = m0 + wr + i * 16 + r0 + q;
          const int gc = n0 + wc + j * 16 + c0;
          float b = acc[i][j][q];
          float a = b2f(Ab[(size_t)gr * 256 + gc]);
          Bv[(size_t)gr * 256 + gc] = f2b(b);
          Gv[(size_t)gr * 256 + gc] = f2b(7.f * a - b);
        }
#pragma unroll
    for (int j = 0; j < 2; j++)
#pragma unroll
      for (int i = 0; i < 2; i++)
#pragma unroll
        for (int q = 0; q < 4; q++) {
          const int gn = n0 + wc + j * 16 + r0 + q;
          const int gm = m0 + wr + i * 16 + c0;
          float bt = accT[j][i][q];
          float at = b2f(Atb[(size_t)gn * 256 + gm]);
          Btv[(size_t)gn * 256 + gm] = f2b(bt);
          Gtv[(size_t)gn * 256 + gm] = f2b(7.f * at - bt);
        }
  } else {
    u16* Wv = p.W + base;
#pragma unroll
    for (int i = 0; i < 2; i++)
#pragma unroll
      for (int j = 0; j < 2; j++)
#pragma unroll
        for (int q = 0; q < 4; q++) {
          const int gr = m0 + wr + i * 16 + r0 + q;
          const int gc = n0 + wc + j * 16 + c0;
          Wv[(size_t)gr * 256 + gc] = f2b(acc[i][j][q]);
        }
  }
}

struct PR2 { const u16 *W, *G, *Gt, *B, *Bt, *z, *A, *At; u16 *zo, *Ao, *Aot; };

__global__ __launch_bounds__(256) void pinv_r2(PR2 p)
{
  __shared__ __align__(16) u16 lds[32768];
  const int tid = threadIdx.x, lane = tid & 63, wid = tid >> 6;
  const int prob = blockIdx.z >> 3;
  const size_t base = (size_t)(blockIdx.z & 7) << 16;
  const u16* U = (prob ? p.G  : p.W ) + base;
  const u16* V = (prob ? p.Bt : p.Gt) + base;
  const int m0 = blockIdx.y * 64, n0 = blockIdx.x * 64;
  const int srow = lane & 15, skoff = (lane >> 4) * 8;
  const int wr = (wid >> 1) * 32, wc = (wid & 1) * 32;

#pragma unroll
  for (int q = 0; q < 16; q++) {
    const int pid = wid * 16 + q;
    const int rg = (pid >> 3) & 3, t = pid & 7;
    const u16* src = (pid < 32)
      ? U + (size_t)(m0 + rg * 16 + srow) * 256 + t * 32 + skoff
      : V + (size_t)(n0 + rg * 16 + srow) * 256 + t * 32 + skoff;
    GLL(src, &lds[pid * 512]);
  }
  asm volatile("s_waitcnt vmcnt(0)" ::: "memory");
  __syncthreads();

  f32x4 acc[2][2], accT[2][2];
#pragma unroll
  for (int i = 0; i < 2; i++)
#pragma unroll
    for (int j = 0; j < 2; j++) {
      acc[i][j] = (f32x4){0.f, 0.f, 0.f, 0.f};
      accT[i][j] = (f32x4){0.f, 0.f, 0.f, 0.f};
    }

#pragma unroll
  for (int t = 0; t < 8; t++) {
    s16x8 afr[2], bfr[2];
#pragma unroll
    for (int i = 0; i < 2; i++)
      afr[i] = *(const s16x8*)&lds[((wr / 16 + i) * 8 + t) * 512 + lane * 8];
#pragma unroll
    for (int j = 0; j < 2; j++)
      bfr[j] = *(const s16x8*)&lds[(32 + (wc / 16 + j) * 8 + t) * 512 + lane * 8];
#pragma unroll
    for (int i = 0; i < 2; i++)
#pragma unroll
      for (int j = 0; j < 2; j++) {
        acc[i][j] = __builtin_amdgcn_mfma_f32_16x16x32_bf16(afr[i], bfr[j], acc[i][j], 0, 0, 0);
        if (prob)
          accT[j][i] = __builtin_amdgcn_mfma_f32_16x16x32_bf16(bfr[j], afr[i], accT[j][i], 0, 0, 0);
      }
  }

  const int r0 = (lane >> 4) * 4, c0 = lane & 15;
  if (prob == 0) {
    const u16* Zb = p.z + base;
    const u16* Wb = p.W + base;
    u16* Zo = p.zo + base;
#pragma unroll
    for (int i = 0; i < 2; i++)
#pragma unroll
      for (int j = 0; j < 2; j++)
#pragma unroll
        for (int q = 0; q < 4; q++) {
          const int gr = m0 + wr + i * 16 + r0 + q;
          const int gc = n0 + wc + j * 16 + c0;
          float v = 0.25f * acc[i][j][q]
                  + 3.25f * b2f(Zb[(size_t)gr * 256 + gc])
                  - 3.75f * b2f(Wb[(size_t)gr * 256 + gc]);
          Zo[(size_t)gr * 256 + gc] = f2b(v);
        }
  } else {
    const u16* Ab  = p.A  + base;
    const u16* Bb  = p.B  + base;
    const u16* Atb = p.At + base;
    const u16* Btb = p.Bt + base;
    u16* Ao  = p.Ao  + base;
    u16* Aot = p.Aot + base;
#pragma unroll
    for (int i = 0; i < 2; i++)
#pragma unroll
      for (int j = 0; j < 2; j++)
#pragma unroll
        for (int q = 0; q < 4; q++) {
          const int gr = m0 + wr + i * 16 + r0 + q;
          const int gc = n0 + wc + j * 16 + c0;
          float v = 0.25f * acc[i][j][q]
                  + 3.25f * b2f(Ab[(size_t)gr * 256 + gc])
                  - 3.75f * b2f(Bb[(size_t)gr * 256 + gc]);
          Ao[(size_t)gr * 256 + gc] = f2b(v);
        }
#pragma unroll
    for (int j = 0; j < 2; j++)
#pragma unroll
      for (int i = 0; i < 2; i++)
#pragma unroll
        for (int q = 0; q < 4; q++) {
          const int gn = n0 + wc + j * 16 + r0 + q;
          const int gm = m0 + wr + i * 16 + c0;
          float v = 0.25f * accT[j][i][q]
                  + 3.25f * b2f(Atb[(size_t)gn * 256 + gm])
                  - 3.75f * b2f(Btb[(size_t)gn * 256 + gm]);
          Aot[(size_t)gn * 256 + gm] = f2b(v);
        }
  }
}

// ---------------------------------------------------------------------------
// prep_weights v2 (kept from R13 — structurally sound, bitwise-identical):
// 64x64 LDS tile transposes, coalesced cold-HBM reads. tile[64][65].
// Grid: 192 blocks (64 Wft + 96 Wqkv + 32 Wout).
// ---------------------------------------------------------------------------
__global__ void prep_weights(const float* __restrict__ Wft, const float* __restrict__ Wqkv,
                             const float* __restrict__ Wout, u16* __restrict__ WftT,
                             u16* __restrict__ WqkvT, u16* __restrict__ WoutT,
                             const float* __restrict__ bout, const float* __restrict__ Wsc,
                             const float* __restrict__ bsc, float* __restrict__ wconst)
{
  __shared__ float tile[64][65];
  const int t = threadIdx.x, col = t & 63, rowg = t >> 6;
  const int b = blockIdx.x;
  const float* src; u16* dst; int ldS, ldD, tr, tc;
  if (b < 64)       { src = Wft;  dst = WftT;  ldS = 256;  ldD = 1024;
                      tr = (b >> 2) * 64;  tc = (b & 3) * 64; }
  else if (b < 160) { int bb = b - 64;  src = Wqkv; dst = WqkvT; ldS = 1536; ldD = 256;
                      tr = (bb / 24) * 64; tc = (bb % 24) * 64; }
  else              { int bb = b - 160; src = Wout; dst = WoutT; ldS = 256;  ldD = 512;
                      tr = (bb >> 2) * 64; tc = (bb & 3) * 64; }
  for (int r = rowg; r < 64; r += 4)
    tile[r][col] = src[(size_t)(tr + r) * ldS + tc + col];
  __syncthreads();
  for (int r = rowg; r < 64; r += 4)
    dst[(size_t)(tc + r) * ldD + tr + col] = f2b(tile[col][r]);

  if (b == 0 && t < 64) {
    // wconst = sum_c b_out[c]*W_score[c] + b_score  (score-combine constant)
    int c = t * 4;
    float s = bout[c] * Wsc[c] + bout[c + 1] * Wsc[c + 1]
            + bout[c + 2] * Wsc[c + 2] + bout[c + 3] * Wsc[c + 3];
    for (int off = 1; off < 64; off <<= 1) s += __shfl_xor(s, off);
    if (t == 0) wconst[0] = s + bsc[0];
  }
}

__global__ void landmark_means(const u16* __restrict__ qkvb,
                               u16* __restrict__ ql, u16* __restrict__ kl)
{
  int idx = blockIdx.x * 256 + threadIdx.x;
  int which = idx >> 17, r = idx & 131071;
  int h = r >> 14, m = (r >> 6) & 255, d = r & 63;
  const u16* src = qkvb + (which ? 512 : 0) + h * 64 + d;
  float s = 0.f; int n0 = m * 32;
  for (int i = 0; i < 32; i++) s += b2f(src[(size_t)(n0 + i) * 1536]);
  (which ? kl : ql)[r] = f2b(s * (1.f / 32.f));
}

__global__ void softmax_rows_bf16_256(u16* __restrict__ d)
{
  const int row = blockIdx.x * 4 + (threadIdx.x >> 6);
  const int lane = threadIdx.x & 63;
  ushort4* p = (ushort4*)(d + (size_t)row * 256);
  ushort4 raw = p[lane];
  float v0 = b2f(raw.x), v1 = b2f(raw.y), v2 = b2f(raw.z), v3 = b2f(raw.w);
  float mx = fmaxf(fmaxf(v0, v1), fmaxf(v2, v3));
  for (int off = 1; off < 64; off <<= 1) mx = fmaxf(mx, __shfl_xor(mx, off));
  v0 = expf(v0 - mx); v1 = expf(v1 - mx); v2 = expf(v2 - mx); v3 = expf(v3 - mx);
  float s = v0 + v1 + v2 + v3;
  for (int off = 1; off < 64; off <<= 1) s += __shfl_xor(s, off);
  float inv = 1.f / s;
  raw.x = f2b(v0 * inv); raw.y = f2b(v1 * inv); raw.z = f2b(v2 * inv); raw.w = f2b(v3 * inv);
  p[lane] = raw;
}

// ---------------------------------------------------------------------------
// reduce_avT (R12-validated): lane index = d -> coalesced avp reads.
// ---------------------------------------------------------------------------
__global__ void reduce_avT(const float* __restrict__ avp, const float* __restrict__ den,
                           u16* __restrict__ avT)
{
  int idx = blockIdx.x * 256 + threadIdx.x;
  int d = idx & 63, m = (idx >> 6) & 255, h = idx >> 14;
  float s = 0.f, l = 0.f;
  for (int c = 0; c < 32; c++) {
    s += avp[((size_t)(h * 32 + c)) * 16384 + m * 64 + d];
    l += den[(size_t)(h * 32 + c) * 256 + m];
  }
  avT[((size_t)h * 64 + d) * 256 + m] = f2b(s / l);
}

// ---------------------------------------------------------------------------
extern "C" void kernel_launch(void* const* d_in, const int* in_sizes, int n_in,
                              void* d_out, int out_size, void* d_ws, size_t ws_size,
                              hipStream_t stream)
{
  const float* x       = (const float*)d_in[0];
  const float* W_ft    = (const float*)d_in[1];
  const float* b_ft    = (const float*)d_in[2];
  const float* W_qkv   = (const float*)d_in[3];
  const float* W_out   = (const float*)d_in[4];
  const float* b_out   = (const float*)d_in[5];
  const float* conv_w  = (const float*)d_in[6];
  const float* W_score = (const float*)d_in[7];
  const float* b_score = (const float*)d_in[8];
  float* out = (float*)d_out;

  char* W = (char*)d_ws;
  auto alloc = [&](size_t bytes) { char* r = W; W += (bytes + 255) & ~(size_t)255; return r; };
  u16* WftT  = (u16*)alloc(256ull * 1024 * 2);
  u16* WqkvT = (u16*)alloc(1536ull * 256 * 2);
  u16* WoutT = (u16*)alloc(256ull * 512 * 2);
  u16* hb    = (u16*)alloc(8192ull * 256 * 2);
  u16* qkvb  = (u16*)alloc(8192ull * 1536 * 2);
  u16* ql    = (u16*)alloc(8ull * 256 * 64 * 2);
  u16* kl    = (u16*)alloc(8ull * 256 * 64 * 2);
  u16* x2    = (u16*)alloc(8ull * 256 * 256 * 2);
  u16* z0    = (u16*)alloc(8ull * 256 * 256 * 2);
  u16* z0T   = (u16*)alloc(8ull * 256 * 256 * 2);
  u16* zp    = (u16*)alloc(8ull * 256 * 256 * 2);   // z pong
  u16* Amat  = (u16*)alloc(8ull * 256 * 256 * 2);   // A ping
  u16* AmatT = (u16*)alloc(8ull * 256 * 256 * 2);
  u16* Am2   = (u16*)alloc(8ull * 256 * 256 * 2);   // A pong
  u16* Am2T  = (u16*)alloc(8ull * 256 * 256 * 2);
  u16* Bm    = (u16*)alloc(8ull * 256 * 256 * 2);   // B = A@A
  u16* BmT   = (u16*)alloc(8ull * 256 * 256 * 2);
  u16* Gm    = (u16*)alloc(8ull * 256 * 256 * 2);   // G = 7A - B
  u16* GmT   = (u16*)alloc(8ull * 256 * 256 * 2);
  u16* Wm    = (u16*)alloc(8ull * 256 * 256 * 2);   // W = z@A
  u16* vT    = (u16*)alloc(8ull * 64 * 8192 * 2);
  float* avp = (float*)alloc(256ull * 16384 * 4);   // split-K 32 partials
  float* denp = (float*)alloc(256ull * 256 * 4);    // exp(S) chunk row-sums
  u16* avT   = (u16*)alloc(8ull * 64 * 256 * 2);
  u16* MmT   = (u16*)alloc(8ull * 64 * 256 * 2);
  u16* af    = (u16*)alloc(8192ull * 512 * 2);
  float* gpart = (float*)alloc(4ull * 8192 * 256 * 4);
  float* sbuf   = (float*)alloc(256);
  float* scores = (float*)alloc(4ull * 8192 * 4);   // split-K score partials
  float* wconst = (float*)alloc(256);

  auto mp = [](const u16* A, const u16* B, int M, int N, int K,
               int lda, int ldb, long long bA, long long bB) {
    MP p{}; p.A = A; p.B = B; p.M = M; p.N = N; p.K = K;
    p.lda = lda; p.ldb = ldb; p.bA = bA; p.bB = bB;
    p.alpha = 1.f; p.beta = 0.f; p.kchunks = 1; return p;
  };

  // 0) weight prep — tiled transposes (coalesced cold-HBM reads) + wconst
  prep_weights<<<192, 256, 0, stream>>>(W_ft, W_qkv, W_out, WftT, WqkvT, WoutT,
                                        b_out, W_score, b_score, wconst);

  // 1) h = relu(x @ W_ft + b_ft) — split-K x4 (proven) + fused reduce
  { MP p = mp((const u16*)x, WftT, 8192, 256, 256, 1024, 1024, 0, 0);
    p.kchunks = 4; p.Cf = gpart; p.ldcf = 256; p.bCf = 2097152;
    gemm_mfma<64, 256, true><<<dim3(1, 128, 4), 256, 0, stream>>>(p); }
  reduce_bias_bf16<<<2048, 256, 0, stream>>>(gpart, b_ft, hb);

  // 2) qkv = h @ W_qkv (q cols x0.125; v side-written transposed)
  { MP p = mp(hb, WqkvT, 8192, 1536, 256, 256, 256, 0, 0);
    p.C = qkvb; p.ldc = 1536; p.scale_cols = 512; p.colscale = 0.125f; p.vTo = vT;
    gemm_mfma<128, 128, false><<<dim3(12, 64, 1), 256, 0, stream>>>(p); }

  // 3) landmark means
  landmark_means<<<1024, 256, 0, stream>>>(qkvb, ql, kl);

  // 4) sim2 = q_l @ k_l^T ; softmax -> attn2 (x2)
  { MP p = mp(ql, kl, 256, 256, 64, 64, 64, 16384, 16384);
    p.C = x2; p.ldc = 256; p.bC = 65536;
    gemm_mfma<64, 64, false><<<dim3(4, 4, 8), 256, 0, stream>>>(p); }
  softmax_rows_bf16_256<<<512, 256, 0, stream>>>(x2);

  // 5+6) pinv — depth-2 coupled iteration (R2-validated):
  prescale<<<16, 256, 0, stream>>>(x2, sbuf);
  pinv_init<<<dim3(16, 8), 256, 0, stream>>>(x2, sbuf, z0, z0T);
  { PG p{x2, z0T, nullptr, nullptr, Amat, AmatT, 1.f, 0.f};
    pinv_gemm<true, true><<<dim3(4, 4, 8), 256, 0, stream>>>(p); }
  {
    const dim3 b(256);
    u16 *zr = z0, *zo = zp;
    u16 *Ar = Amat, *Art = AmatT, *Ao = Am2, *Aot = Am2T;
    for (int it = 0; it < 6; it++) {
      { PR1 r{Ar, Art, zr, Bm, BmT, Gm, GmT, Wm};
        pinv_r1<<<dim3(4, 4, 16), b, 0, stream>>>(r); }
      { PR2 r{Wm, Gm, GmT, Bm, BmT, zr, Ar, Art, zo, Ao, Aot};
        pinv_r2<<<dim3(4, 4, (it == 5) ? 8 : 16), b, 0, stream>>>(r); }
      u16* t;
      t = zr; zr = zo; zo = t;
      t = Ar; Ar = Ao; Ao = t;
      t = Art; Art = Aot; Aot = t;
    }
  }
  // final z row-major in z0 (6 swaps -> zr == z0)

  // 7+8) av = softmax(q_l @ k^T) @ v — fully fused, split-K 32 (2 blocks/CU).
  { AVF p{qkvb, ql, vT, avp, denp};
    av_fused<<<dim3(1, 2, 256), 256, 0, stream>>>(p); }
  reduce_avT<<<512, 256, 0, stream>>>(avp, denp, avT);

  // 9) MmT = (pinv @ av)^T
  { MP p = mp(z0, avT, 256, 64, 256, 256, 256, 65536, 16384);
    p.Ct = MmT; p.ldct = 256; p.bCt = 16384;
    gemm_mfma<64, 64, false><<<dim3(1, 4, 8), 256, 0, stream>>>(p); }

  // 10+11) af = softmax(q @ k_l^T) @ Mm — fused (staged GLL form, proven)
  { FA1 fp{qkvb, kl, MmT, af};
    fused_attn1<<<dim3(128, 8), 256, 0, stream>>>(fp); }

  // 12) af += depthwise conv(v) — standalone (proven layout)
  conv_res_add_bf16<<<dim3(128, 8), 256, 0, stream>>>(qkvb, conv_w, af);

  // 13) score partials: split-K x4, per-chunk row-dot with W_score in the
  // epilogue — af_out never materialized.
  { MP p = mp(af, WoutT, 8192, 256, 128, 512, 512, 0, 0);
    p.kchunks = 4; p.Ws = W_score; p.sc = scores;
    gemm_mfma<64, 256, false><<<dim3(1, 128, 4), 256, 0, stream>>>(p); }

  // 14+15+16) weights = softmax(scores); aggregated = weights @ h — fused
  // (257-block R12 form)
  fused_tail<<<257, 256, 0, stream>>>(scores, wconst, hb, out);
}